// Round 10
// baseline (110.196 us; speedup 1.0000x reference)
//
#include <hip/hip_runtime.h>
#include <math.h>

// Problem constants (fixed by reference)
#define BATCH 2
#define SEQ   1024
#define DM    1024   // D_MODEL
#define MMEM  128    // memory slots
#define MEMD  512    // MEM_DIM
#define RELH  512    // REL_HID
#define KVLD  2560   // ld of combined [keys|values|m_part]
#define QLD   1536   // ld of combined [queries|q_part]

typedef _Float16 f16;
typedef __attribute__((ext_vector_type(2))) _Float16 f16x2;
typedef __attribute__((ext_vector_type(4))) _Float16 f16x4;
typedef __attribute__((ext_vector_type(8))) _Float16 f16x8;
typedef __attribute__((ext_vector_type(4))) float    f32x4;

__device__ inline float dot2acc(f16x2 a, f16x2 b, float c) {
#if __has_builtin(__builtin_amdgcn_fdot2)
    return __builtin_amdgcn_fdot2(a, b, c, false);
#else
    return c + (float)a[0] * (float)b[0] + (float)a[1] * (float)b[1];
#endif
}
__device__ inline f16x2 relu2(f16x2 a) {
    f16x2 z = { (_Float16)0.0f, (_Float16)0.0f };
#if __has_builtin(__builtin_elementwise_max)
    return __builtin_elementwise_max(a, z);
#else
    f16x2 r;
    r[0] = a[0] > z[0] ? a[0] : z[0];
    r[1] = a[1] > z[1] ? a[1] : z[1];
    return r;
#endif
}

// async global->LDS, 16B per lane (wave-uniform LDS base + lane*16)
__device__ inline void llds16(const void* gp, void* lp) {
    __builtin_amdgcn_global_load_lds(
        (const __attribute__((address_space(1))) void*)gp,
        (__attribute__((address_space(3))) void*)lp,
        16, 0, 0);
}

__device__ inline void cast8(const float* __restrict__ in, f16* __restrict__ out, int i) {
    const float4* p = (const float4*)in + (size_t)i * 2;
    float4 a = p[0], b = p[1];
    f16x8 v = { (f16)a.x, (f16)a.y, (f16)a.z, (f16)a.w,
                (f16)b.x, (f16)b.y, (f16)b.z, (f16)b.w };
    *(f16x8*)(out + (size_t)i * 8) = v;
}

__device__ inline void tr_tile(float (*t)[65], const float* __restrict__ in,
                               f16* __restrict__ out, int R, int C, int tile) {
    const int tid = threadIdx.x;
    const int ctiles = C >> 6;
    const int r0 = (tile / ctiles) * 64, c0 = (tile % ctiles) * 64;
    #pragma unroll
    for (int i = 0; i < 16; ++i) {
        int idx = tid + 256 * i;
        int r = idx >> 6, c = idx & 63;
        t[c][r] = in[(size_t)(r0 + r) * C + c0 + c];
    }
    __syncthreads();
    #pragma unroll
    for (int i = 0; i < 16; ++i) {
        int idx = tid + 256 * i;
        int ro = idx >> 6, co = idx & 63;
        out[(size_t)(c0 + ro) * R + r0 + co] = (f16)t[ro][co];
    }
}

// ---------------------------------------------------------------------------
// MFMA GEMM core: C(f32,opt)/C2(f16,opt) = A @ Bt^T + bias(local col index).
// BM=64, BN=128, BK=64, 256 thr = 4 waves, double-buffered LDS (48 KB).
// Staging modes per operand:
//   0: f16 source via global_load_lds (inverse-swizzled source, linear LDS)
//   1: f32 source, row-major [r][k]; reg-staged cast (load early, cvt+ds_write
//      late) into the same XOR-swizzled layout    [proven R9]
//   2: f32 source, column gather: elem[r][k] = src[k*ld + r] (i.e. implicit
//      transpose of a k-major weight); same reg->LDS write path as mode 1.
// LDS[row][slot s] = elem[row][chunk s ^ (row&7)], chunk = 8 f16.
// ---------------------------------------------------------------------------
template<int BM, int BN, int AMODE, int BMODE>
__device__ __forceinline__ void gemm_core(
    const f16* __restrict__ Ah, const float* __restrict__ Af,
    const f16* __restrict__ Bth, const float* __restrict__ Btf,
    const float* __restrict__ bias, float* __restrict__ C,
    f16* __restrict__ C2, int K, int ldc, int lda, int ldb,
    int bx, int by, f16* Al, f16* Bl)
{
    constexpr int MF   = BM / 16;
    constexpr int NF   = BN / 64;
    constexpr int ABUF = BM * 64;
    constexpr int BBUF = BN * 64;
    const int tid = threadIdx.x, lane = tid & 63, wid = tid >> 6;
    const size_t row0 = (size_t)by * BM;
    const size_t col0 = (size_t)bx * BN;
    const int lrow = lane >> 3;
    const int lcs  = (lane & 7) ^ lrow;
    const int r15 = lane & 15, l4 = lane >> 4;
    const int crow = tid >> 2, ckc = tid & 3;

    f32x4 acc[MF][NF];
    #pragma unroll
    for (int m = 0; m < MF; ++m)
        #pragma unroll
        for (int n = 0; n < NF; ++n) acc[m][n] = (f32x4){0.f, 0.f, 0.f, 0.f};

    float4 aregs[(AMODE != 0) ? (BM / 64) : 1][4];
    float4 bregs[(BMODE != 0) ? (BN / 64) : 1][4];

    auto LOAD_A = [&](int kt) {
        if constexpr (AMODE == 1) {
            #pragma unroll
            for (int g = 0; g < BM / 64; ++g) {
                const float* src = Af + (row0 + g * 64 + crow) * (size_t)lda
                                      + kt * 64 + ckc * 16;
                #pragma unroll
                for (int q = 0; q < 4; ++q) aregs[g][q] = *(const float4*)(src + q * 4);
            }
        } else if constexpr (AMODE == 2) {
            #pragma unroll
            for (int g = 0; g < BM / 64; ++g) {
                const size_t mm = row0 + g * 64 + crow;
                #pragma unroll
                for (int q = 0; q < 4; ++q) {
                    const int kb = kt * 64 + ckc * 16 + q * 4;
                    aregs[g][q] = make_float4(
                        Af[(size_t)(kb + 0) * lda + mm],
                        Af[(size_t)(kb + 1) * lda + mm],
                        Af[(size_t)(kb + 2) * lda + mm],
                        Af[(size_t)(kb + 3) * lda + mm]);
                }
            }
        }
    };
    auto LOAD_B = [&](int kt) {
        if constexpr (BMODE == 1) {
            #pragma unroll
            for (int g = 0; g < BN / 64; ++g) {
                const float* src = Btf + (col0 + g * 64 + crow) * (size_t)ldb
                                       + kt * 64 + ckc * 16;
                #pragma unroll
                for (int q = 0; q < 4; ++q) bregs[g][q] = *(const float4*)(src + q * 4);
            }
        } else if constexpr (BMODE == 2) {
            #pragma unroll
            for (int g = 0; g < BN / 64; ++g) {
                const size_t nn = col0 + g * 64 + crow;
                #pragma unroll
                for (int q = 0; q < 4; ++q) {
                    const int kb = kt * 64 + ckc * 16 + q * 4;
                    bregs[g][q] = make_float4(
                        Btf[(size_t)(kb + 0) * ldb + nn],
                        Btf[(size_t)(kb + 1) * ldb + nn],
                        Btf[(size_t)(kb + 2) * ldb + nn],
                        Btf[(size_t)(kb + 3) * ldb + nn]);
                }
            }
        }
    };
    auto WRITE_A = [&](int buf) {
        if constexpr (AMODE != 0) {
            #pragma unroll
            for (int g = 0; g < BM / 64; ++g) {
                const int row = g * 64 + crow;
                f16x8 h0 = { (f16)aregs[g][0].x, (f16)aregs[g][0].y,
                             (f16)aregs[g][0].z, (f16)aregs[g][0].w,
                             (f16)aregs[g][1].x, (f16)aregs[g][1].y,
                             (f16)aregs[g][1].z, (f16)aregs[g][1].w };
                f16x8 h1 = { (f16)aregs[g][2].x, (f16)aregs[g][2].y,
                             (f16)aregs[g][2].z, (f16)aregs[g][2].w,
                             (f16)aregs[g][3].x, (f16)aregs[g][3].y,
                             (f16)aregs[g][3].z, (f16)aregs[g][3].w };
                f16* base = Al + buf * ABUF + row * 64;
                *(f16x8*)(base + (((ckc * 2 + 0) ^ (row & 7)) * 8)) = h0;
                *(f16x8*)(base + (((ckc * 2 + 1) ^ (row & 7)) * 8)) = h1;
            }
        }
    };
    auto WRITE_B = [&](int buf) {
        if constexpr (BMODE != 0) {
            #pragma unroll
            for (int g = 0; g < BN / 64; ++g) {
                const int row = g * 64 + crow;
                f16x8 h0 = { (f16)bregs[g][0].x, (f16)bregs[g][0].y,
                             (f16)bregs[g][0].z, (f16)bregs[g][0].w,
                             (f16)bregs[g][1].x, (f16)bregs[g][1].y,
                             (f16)bregs[g][1].z, (f16)bregs[g][1].w };
                f16x8 h1 = { (f16)bregs[g][2].x, (f16)bregs[g][2].y,
                             (f16)bregs[g][2].z, (f16)bregs[g][2].w,
                             (f16)bregs[g][3].x, (f16)bregs[g][3].y,
                             (f16)bregs[g][3].z, (f16)bregs[g][3].w };
                f16* base = Bl + buf * BBUF + row * 64;
                *(f16x8*)(base + (((ckc * 2 + 0) ^ (row & 7)) * 8)) = h0;
                *(f16x8*)(base + (((ckc * 2 + 1) ^ (row & 7)) * 8)) = h1;
            }
        }
    };
    auto STAGE_A16 = [&](int buf, int kt) {
        if constexpr (AMODE == 0) {
            const f16* Ab = Ah + row0 * lda + (size_t)kt * 64;
            #pragma unroll
            for (int j = 0; j < BM / 32; ++j) {
                const int c = wid * (BM / 32) + j;
                llds16(Ab + (size_t)(c * 8 + lrow) * lda + lcs * 8,
                       Al + buf * ABUF + c * 512);
            }
        }
    };
    auto STAGE_B16 = [&](int buf, int kt) {
        if constexpr (BMODE == 0) {
            const f16* Bb = Bth + col0 * ldb + (size_t)kt * 64;
            #pragma unroll
            for (int j = 0; j < BN / 32; ++j) {
                const int c = wid * (BN / 32) + j;
                llds16(Bb + (size_t)(c * 8 + lrow) * ldb + lcs * 8,
                       Bl + buf * BBUF + c * 512);
            }
        }
    };

    LOAD_A(0); LOAD_B(0);
    STAGE_A16(0, 0); STAGE_B16(0, 0);
    WRITE_A(0); WRITE_B(0);
    __syncthreads();

    const int nk = K >> 6;
    int cur = 0;
    for (int kt = 0; kt < nk; ++kt) {
        const bool more = (kt + 1 < nk);
        if (more) {
            STAGE_A16(cur ^ 1, kt + 1);
            STAGE_B16(cur ^ 1, kt + 1);
            LOAD_A(kt + 1);
            LOAD_B(kt + 1);
        }
        #pragma unroll
        for (int kk = 0; kk < 2; ++kk) {
            f16x8 af[MF], bfr[NF];
            #pragma unroll
            for (int m = 0; m < MF; ++m) {
                const int rowA = m * 16 + r15;
                af[m] = *(const f16x8*)(Al + cur * ABUF + rowA * 64 +
                                        (((kk * 4 + l4) ^ (r15 & 7)) * 8));
            }
            #pragma unroll
            for (int n = 0; n < NF; ++n) {
                const int rowB = wid * (BN / 4) + n * 16 + r15;
                bfr[n] = *(const f16x8*)(Bl + cur * BBUF + rowB * 64 +
                                         (((kk * 4 + l4) ^ (r15 & 7)) * 8));
            }
            #pragma unroll
            for (int m = 0; m < MF; ++m)
                #pragma unroll
                for (int n = 0; n < NF; ++n)
                    acc[m][n] = __builtin_amdgcn_mfma_f32_16x16x32_f16(
                        af[m], bfr[n], acc[m][n], 0, 0, 0);
        }
        if (more) { WRITE_A(cur ^ 1); WRITE_B(cur ^ 1); }
        __syncthreads();
        cur ^= 1;
    }

    // C/D layout: col = lane&15, row = (lane>>4)*4 + j
    const int cr = l4, cc = r15;
    #pragma unroll
    for (int n = 0; n < NF; ++n) {
        const size_t col = col0 + wid * (BN / 4) + n * 16 + cc;
        const float bvv = bias ? bias[(int)(col - col0)] : 0.f;
        #pragma unroll
        for (int m = 0; m < MF; ++m) {
            #pragma unroll
            for (int j = 0; j < 4; ++j) {
                const size_t row = row0 + m * 16 + cr * 4 + j;
                const float v = acc[m][n][j] + bvv;
                if (C)  C[row * ldc + col] = v;
                if (C2) C2[row * ldc + col] = (f16)v;
            }
        }
    }
}

// ---------------------------------------------------------------------------
// L1: hs cast + Wq^T/Wo^T transposes + kvm GEMM (raw f32 weights, gather-B)
//     + wq1t GEMM (gather-A W1q^T, cast-B Wq) + bq@W1q reduction.
// grid 1688 x 256. Blocks:
//   [0,1024)     hs f32->f16
//   [1024,1280)  Wq^T  -> btbig rows [0,1024)
//   [1280,1536)  Wo^T  -> Wo_t
//   [1536,1616)  kvm = mem @ [Wk|Wv|W1m] + [bk|bv|b1]
//   [1616,1680)  wq1t = W1q^T @ Wq^T -> btbig rows [1024,1536)
//   [1680,1688)  bqh[j] = sum_k bq[k] * W1q[k][j]
// ---------------------------------------------------------------------------
__global__ __launch_bounds__(256) void prep2(
    const float* __restrict__ hs, const float* __restrict__ mem,
    const float* __restrict__ Wq, const float* __restrict__ Wk,
    const float* __restrict__ Wv, const float* __restrict__ Wo,
    const float* __restrict__ W1,
    const float* __restrict__ bk, const float* __restrict__ bv,
    const float* __restrict__ b1, const float* __restrict__ bq,
    f16* __restrict__ hs_f16, f16* __restrict__ btbig,
    f16* __restrict__ Wo_t, f16* __restrict__ kvm,
    float* __restrict__ bqh)
{
    __shared__ __align__(16) char smem[49152];
    const int bid = blockIdx.x, tid = threadIdx.x;

    if (bid < 1024) {
        cast8(hs, hs_f16, bid * 256 + tid);
    } else if (bid < 1280) {
        tr_tile((float(*)[65])smem, Wq, btbig, 1024, 1024, bid - 1024);
    } else if (bid < 1536) {
        tr_tile((float(*)[65])smem, Wo, Wo_t, 1024, 1024, bid - 1280);
    } else if (bid < 1616) {
        const int i = bid - 1536;           // 20 bx x 4 by
        const int bx = i % 20, by = i / 20;
        const float* Wseg; const float* bseg; int ldb;
        if (bx < 8)       { Wseg = Wk;                          bseg = bk + bx * 128;          ldb = 1024; }
        else if (bx < 16) { Wseg = Wv - (size_t)1024;           bseg = bv + (bx * 128 - 1024); ldb = 1024; }
        else              { Wseg = W1 + (size_t)1024 * 512 - 2048; bseg = b1 + (bx * 128 - 2048); ldb = 512; }
        gemm_core<64, 128, 1, 2>(
            nullptr, mem, nullptr, Wseg, bseg, nullptr, kvm,
            MEMD, KVLD, MEMD, ldb, bx, by,
            (f16*)smem, (f16*)(smem + 16384));
    } else if (bid < 1680) {
        const int i = bid - 1616;           // 8 bx x 8 by
        gemm_core<64, 128, 2, 1>(
            nullptr, W1, nullptr, Wq, nullptr, nullptr,
            btbig + (size_t)1024 * DM,
            DM, DM, RELH /*lda: W1 row stride*/, DM, i % 8, i / 8,
            (f16*)smem, (f16*)(smem + 16384));
    } else {
        // bqh[p*64 + j] = sum_k bq[k] * W1[k][p*64+j]
        const int p = bid - 1680;
        const int jl = tid & 63, slab = tid >> 6;
        float part = 0.f;
        const int k0 = slab * 256;
        for (int k = k0; k < k0 + 256; ++k)
            part += bq[k] * W1[(size_t)k * 512 + p * 64 + jl];
        float* red = (float*)smem;
        red[slab * 64 + jl] = part;
        __syncthreads();
        if (tid < 64)
            bqh[p * 64 + tid] = red[tid] + red[64 + tid] + red[128 + tid] + red[192 + tid];
    }
}

// ---------------------------------------------------------------------------
// L2: qcat GEMM (384) + VoT GEMM (32) + mpt (8). grid 424 x 256.
// ---------------------------------------------------------------------------
__global__ __launch_bounds__(256) void midgemm(
    const f16* __restrict__ hs_f16, const f16* __restrict__ btbig,
    const float* __restrict__ bq, const float* __restrict__ bqh,
    f16* __restrict__ qcat, const f16* __restrict__ kvm,
    const f16* __restrict__ Wo_t, f16* __restrict__ VoT,
    f16* __restrict__ mpt)
{
    __shared__ __align__(16) char smem[49152];
    const int bid = blockIdx.x, tid = threadIdx.x;

    if (bid < 384) {
        const int bx = bid % 12, by = bid / 12;
        const float* bias = (bx < 8) ? (bq + bx * 128) : (bqh + (bx - 8) * 128);
        gemm_core<64, 128, 0, 0>(
            hs_f16, nullptr, btbig, nullptr, bias, nullptr, qcat,
            DM, QLD, DM, DM, bx, by,
            (f16*)smem, (f16*)(smem + 16384));
        return;
    }
    if (bid < 416) {
        // VoT = Wo_t @ values^T (values = kvm cols [1024,2048), +bv folded)
        const int i = bid - 384;
        gemm_core<64, 128, 0, 0>(
            Wo_t, nullptr, kvm + 1024, nullptr, nullptr, nullptr, VoT,
            DM, 256, DM, KVLD, i % 2, i / 2,
            (f16*)smem, (f16*)(smem + 16384));
        return;
    }
    // mpt: m_part rows (kvm cols 2048..2560) -> [b][256 h2][128 m][2]
    f16 (*t2)[136] = (f16(*)[136])smem;
    const f16* mpart = kvm + 2048;
    const int mb = bid - 416, b = mb >> 2, hc = mb & 3;
    #pragma unroll
    for (int k = 0; k < 8; ++k) {
        int idx = tid + 256 * k;
        int m = idx >> 4, hq = idx & 15;
        *(f16x8*)(&t2[m][hq * 8]) =
            *(const f16x8*)(mpart + (size_t)(b * 128 + m) * KVLD + hc * 128 + hq * 8);
    }
    __syncthreads();
    #pragma unroll
    for (int k = 0; k < 32; ++k) {
        int idx = tid + 256 * k;
        int h2l = idx >> 7, m = idx & 127;
        f16x2 v = { t2[m][h2l * 2], t2[m][h2l * 2 + 1] };
        *(f16x2*)(mpt + ((size_t)b * 256 + hc * 64 + h2l) * 256 + m * 2) = v;
    }
}

// ---------------------------------------------------------------------------
// L3: fused relevance + scores + softmax + P@Vo + bo -> out (f32).
// grid 256 x 256 (8 s-rows/block). Verbatim from R8 (passing).
// ---------------------------------------------------------------------------
__global__ __launch_bounds__(256) void relattn(
    const f16* __restrict__ qcat,    // [2048][QLD]: queries | q_part
    const f16* __restrict__ kvm,     // [256][KVLD]: keys in cols [0,1024)
    const f16* __restrict__ VoT,     // [1024][256]
    const f16* __restrict__ mpt,     // [b][256 h2][128 m][2]
    const float* __restrict__ W2,    // [512]
    const float* __restrict__ b2,    // [1]
    const float* __restrict__ bo,    // [1024]
    float* __restrict__ out,         // [2048][1024] f32
    float* __restrict__ attn_w)      // [2048][128]
{
    __shared__ __align__(16) char u[41984];      // qs|mps|w2s  then  sc
    __shared__ float rel_s[1024];                // [8][128] persistent
    __shared__ f16 Ps[8 * 136];

    const int tid = threadIdx.x;
    const int b = blockIdx.x >> 7, st = blockIdx.x & 127;
    const size_t rowbase = (size_t)b * SEQ + st * 8;
    const int w = tid >> 6, lane = tid & 63;
    const int l15 = lane & 15, l4 = lane >> 4;

    // ---------------- Phase R: relevance -> rel_s ----------------
    {
        f16* qs  = (f16*)u;                 // [8][512]  8 KB
        f16* mps = (f16*)(u + 8192);        // [64][256] 32 KB
        f16* w2s = (f16*)(u + 40960);       // [512]     1 KB

        {
            int r = tid >> 5, c = tid & 31;
            const f16* src = qcat + (rowbase + r) * QLD + 1024 + c * 16;
            *(f16x8*)(qs + r * 512 + c * 16)     = *(const f16x8*)(src);
            *(f16x8*)(qs + r * 512 + c * 16 + 8) = *(const f16x8*)(src + 8);
        }
        if (tid < 128) {
            float4 w4 = *(const float4*)(W2 + tid * 4);
            f16x4 hv = { (f16)w4.x, (f16)w4.y, (f16)w4.z, (f16)w4.w };
            *(f16x4*)(w2s + tid * 4) = hv;
        }
        const float b2v = b2[0];
        const int sg = w;

        float acc00 = 0.f, acc01 = 0.f, acc10 = 0.f, acc11 = 0.f;
        const f16* mptb = mpt + (size_t)b * 65536;

        for (int hc = 0; hc < 4; ++hc) {
            __syncthreads();
            {
                const f16x8* src = (const f16x8*)(mptb + hc * 16384);
                f16x8* dst = (f16x8*)mps;
                #pragma unroll
                for (int k = 0; k < 8; ++k) dst[tid + 256 * k] = src[tid + 256 * k];
            }
            __syncthreads();

            #pragma unroll 4
            for (int step = 0; step < 16; ++step) {
                const int habs = hc * 128 + step * 8;
                uint4 q0u = *(const uint4*)(qs + (2 * sg) * 512 + habs);
                uint4 q1u = *(const uint4*)(qs + (2 * sg + 1) * 512 + habs);
                uint4 wu  = *(const uint4*)(w2s + habs);
                const unsigned* q0p = (const unsigned*)&q0u;
                const unsigned* q1p = (const unsigned*)&q1u;
                const unsigned* wp_ = (const unsigned*)&wu;
                #pragma unroll
                for (int jj = 0; jj < 4; ++jj) {
                    uint2 mpu = *(const uint2*)(mps + ((step * 4 + jj) * 128 + 2 * lane) * 2);
                    f16x2 m0 = __builtin_bit_cast(f16x2, mpu.x);
                    f16x2 m1 = __builtin_bit_cast(f16x2, mpu.y);
                    f16x2 wp = __builtin_bit_cast(f16x2, wp_[jj]);
                    f16x2 q0 = __builtin_bit_cast(f16x2, q0p[jj]);
                    f16x2 q1 = __builtin_bit_cast(f16x2, q1p[jj]);
                    acc00 = dot2acc(relu2(q0 + m0), wp, acc00);
                    acc01 = dot2acc(relu2(q0 + m1), wp, acc01);
                    acc10 = dot2acc(relu2(q1 + m0), wp, acc10);
                    acc11 = dot2acc(relu2(q1 + m1), wp, acc11);
                }
            }
        }

        rel_s[(2 * sg) * 128 + 2 * lane]         = 1.f / (1.f + __expf(-(acc00 + b2v)));
        rel_s[(2 * sg) * 128 + 2 * lane + 1]     = 1.f / (1.f + __expf(-(acc01 + b2v)));
        rel_s[(2 * sg + 1) * 128 + 2 * lane]     = 1.f / (1.f + __expf(-(acc10 + b2v)));
        rel_s[(2 * sg + 1) * 128 + 2 * lane + 1] = 1.f / (1.f + __expf(-(acc11 + b2v)));
    }
    __syncthreads();   // rel_s ready; qs/mps dead -> sc may overwrite

    float* sc = (float*)u;   // [4][16][128] 32 KB

    // ---------------- Phase S: QK^T partials over k-quarter ----------------
    {
        f32x4 aq[8];
        #pragma unroll
        for (int n = 0; n < 8; ++n) aq[n] = (f32x4){0.f, 0.f, 0.f, 0.f};
        #pragma unroll
        for (int k4 = 0; k4 < 8; ++k4) {
            const int k0 = w * 256 + k4 * 32 + l4 * 8;
            f16x8 af = *(const f16x8*)(qcat + (rowbase + (l15 & 7)) * QLD + k0);
            #pragma unroll
            for (int n = 0; n < 8; ++n) {
                f16x8 bf = *(const f16x8*)(kvm + (size_t)(b * 128 + n * 16 + l15) * KVLD + k0);
                aq[n] = __builtin_amdgcn_mfma_f32_16x16x32_f16(af, bf, aq[n], 0, 0, 0);
            }
        }
        #pragma unroll
        for (int n = 0; n < 8; ++n)
            #pragma unroll
            for (int j = 0; j < 4; ++j)
                sc[(w * 16 + l4 * 4 + j) * 128 + n * 16 + l15] = aq[n][j];
    }
    __syncthreads();

    // ---------------- reduce partials, *rel/32, softmax ----------------
    {
        const int r = tid >> 5, seg = tid & 31;
        float4 xs = {0.f, 0.f, 0.f, 0.f};
        #pragma unroll
        for (int ww = 0; ww < 4; ++ww) {
            float4 p = *(const float4*)(sc + (ww * 16 + r) * 128 + seg * 4);
            xs.x += p.x; xs.y += p.y; xs.z += p.z; xs.w += p.w;
        }
        float4 rl = *(const float4*)(rel_s + r * 128 + seg * 4);
        float x[4];
        x[0] = xs.x * 0.03125f * rl.x; x[1] = xs.y * 0.03125f * rl.y;
        x[2] = xs.z * 0.03125f * rl.z; x[3] = xs.w * 0.03125f * rl.w;
        float mx = fmaxf(fmaxf(x[0], x[1]), fmaxf(x[2], x[3]));
        #pragma unroll
        for (int d = 1; d < 32; d <<= 1) mx = fmaxf(mx, __shfl_xor(mx, d));
        float ss = 0.f;
        #pragma unroll
        for (int c = 0; c < 4; ++c) { x[c] = __expf(x[c] - mx); ss += x[c]; }
        #pragma unroll
        for (int d = 1; d < 32; d <<= 1) ss += __shfl_xor(ss, d);
        const float inv = 1.f / ss;
        #pragma unroll
        for (int c = 0; c < 4; ++c) x[c] *= inv;
        float4 o = { x[0], x[1], x[2], x[3] };
        *(float4*)(attn_w + (rowbase + r) * 128 + seg * 4) = o;
        f16x4 ph = { (f16)x[0], (f16)x[1], (f16)x[2], (f16)x[3] };
        *(f16x4*)(Ps + r * 136 + seg * 4) = ph;
    }
    __syncthreads();

    // ---------------- Phase P: out = P @ Vo + bo over d-quarter ----------------
    {
        f16x8 pa[4];
        #pragma unroll
        for (int k = 0; k < 4; ++k)
            pa[k] = *(const f16x8*)(Ps + (l15 & 7) * 136 + k * 32 + l4 * 8);
        #pragma unroll
        for (int n2 = 0; n2 < 16; ++n2) {
            f32x4 ac = (f32x4){0.f, 0.f, 0.f, 0.f};
            const int d0 = w * 256 + n2 * 16;
            #pragma unroll
            for (int k = 0; k < 4; ++k) {
                f16x8 bf = *(const f16x8*)(VoT + (size_t)(d0 + l15) * 256 + b * 128 + k * 32 + l4 * 8);
                ac = __builtin_amdgcn_mfma_f32_16x16x32_f16(pa[k], bf, ac, 0, 0, 0);
            }
            if (l4 < 2) {
                const float bov = bo[d0 + l15];
                #pragma unroll
                for (int j = 0; j < 4; ++j)
                    out[(rowbase + l4 * 4 + j) * 1024 + d0 + l15] = ac[j] + bov;
            }
        }
    }
}

// ---------------------------------------------------------------------------
extern "C" void kernel_launch(void* const* d_in, const int* in_sizes, int n_in,
                              void* d_out, int out_size, void* d_ws, size_t ws_size,
                              hipStream_t stream)
{
    const float* hs  = (const float*)d_in[0];
    const float* mem = (const float*)d_in[1];
    const float* Wq  = (const float*)d_in[2];
    const float* bq  = (const float*)d_in[3];
    const float* Wk  = (const float*)d_in[4];
    const float* bk  = (const float*)d_in[5];
    const float* Wv  = (const float*)d_in[6];
    const float* bv  = (const float*)d_in[7];
    const float* Wo  = (const float*)d_in[8];
    const float* bo  = (const float*)d_in[9];
    const float* W1  = (const float*)d_in[10];  // (1536,512)
    const float* b1  = (const float*)d_in[11];
    const float* W2  = (const float*)d_in[12];
    const float* b2  = (const float*)d_in[13];

    float* out   = (float*)d_out;                       // (2,1024,1024)
    float* attnw = out + (size_t)BATCH * SEQ * DM;      // (2,1024,128)

    // workspace layout (16B-aligned, ~17 MB)
    char* wp = (char*)d_ws;
    f16* hs_f16 = (f16*)wp;  wp += (size_t)BATCH * SEQ * DM * 2;     // 4 MB
    f16* btbig  = (f16*)wp;  wp += (size_t)QLD * DM * 2;             // 3 MB
    f16* Wo_t   = (f16*)wp;  wp += (size_t)DM * DM * 2;              // 2 MB
    f16* qcat   = (f16*)wp;  wp += (size_t)BATCH * SEQ * QLD * 2;    // 6 MB
    f16* kvm    = (f16*)wp;  wp += (size_t)BATCH * MMEM * KVLD * 2;  // 1.25 MB
    f16* VoT    = (f16*)wp;  wp += (size_t)DM * BATCH * MMEM * 2;    // 0.5 MB
    f16* mpt    = (f16*)wp;  wp += (size_t)BATCH * MMEM * RELH * 2;  // 0.25 MB
    float* bqh  = (float*)wp; wp += (size_t)RELH * 4;                // 2 KB

    dim3 blk(256);

    // L1: casts + transposes + kvm/wq1t GEMMs (raw f32 weights) + bqh
    prep2<<<dim3(1688), blk, 0, stream>>>(
        hs, mem, Wq, Wk, Wv, Wo, W1, bk, bv, b1, bq,
        hs_f16, btbig, Wo_t, kvm, bqh);

    // L2: qcat GEMM + VoT GEMM + mpt
    midgemm<<<dim3(424), blk, 0, stream>>>(
        hs_f16, btbig, bq, bqh, qcat, kvm, Wo_t, VoT, mpt);

    // L3: fused relevance + attention -> out, attn_w
    relattn<<<dim3(256), blk, 0, stream>>>(
        qcat, kvm, VoT, mpt, W2, b2, bo, out, attnw);
}

// Round 11
// 103.360 us; speedup vs baseline: 1.0661x; 1.0661x over previous
//
#include <hip/hip_runtime.h>
#include <math.h>

// Problem constants (fixed by reference)
#define BATCH 2
#define SEQ   1024
#define DM    1024   // D_MODEL
#define MMEM  128    // memory slots
#define MEMD  512    // MEM_DIM
#define RELH  512    // REL_HID
#define KVLD  2560   // ld of combined [keys|values|m_part]
#define QLD   1536   // ld of combined [queries|q_part]

typedef _Float16 f16;
typedef __attribute__((ext_vector_type(2))) _Float16 f16x2;
typedef __attribute__((ext_vector_type(4))) _Float16 f16x4;
typedef __attribute__((ext_vector_type(8))) _Float16 f16x8;
typedef __attribute__((ext_vector_type(4))) float    f32x4;

__device__ inline float dot2acc(f16x2 a, f16x2 b, float c) {
#if __has_builtin(__builtin_amdgcn_fdot2)
    return __builtin_amdgcn_fdot2(a, b, c, false);
#else
    return c + (float)a[0] * (float)b[0] + (float)a[1] * (float)b[1];
#endif
}
__device__ inline f16x2 relu2(f16x2 a) {
    f16x2 z = { (_Float16)0.0f, (_Float16)0.0f };
#if __has_builtin(__builtin_elementwise_max)
    return __builtin_elementwise_max(a, z);
#else
    f16x2 r;
    r[0] = a[0] > z[0] ? a[0] : z[0];
    r[1] = a[1] > z[1] ? a[1] : z[1];
    return r;
#endif
}

// async global->LDS, 16B per lane (wave-uniform LDS base + lane*16)
__device__ inline void llds16(const void* gp, void* lp) {
    __builtin_amdgcn_global_load_lds(
        (const __attribute__((address_space(1))) void*)gp,
        (__attribute__((address_space(3))) void*)lp,
        16, 0, 0);
}

__device__ inline void cast8(const float* __restrict__ in, f16* __restrict__ out, int i) {
    const float4* p = (const float4*)in + (size_t)i * 2;
    float4 a = p[0], b = p[1];
    f16x8 v = { (f16)a.x, (f16)a.y, (f16)a.z, (f16)a.w,
                (f16)b.x, (f16)b.y, (f16)b.z, (f16)b.w };
    *(f16x8*)(out + (size_t)i * 8) = v;
}

__device__ inline void tr_tile(float (*t)[65], const float* __restrict__ in,
                               f16* __restrict__ out, int R, int C, int tile) {
    const int tid = threadIdx.x;
    const int ctiles = C >> 6;
    const int r0 = (tile / ctiles) * 64, c0 = (tile % ctiles) * 64;
    #pragma unroll
    for (int i = 0; i < 16; ++i) {
        int idx = tid + 256 * i;
        int r = idx >> 6, c = idx & 63;
        t[c][r] = in[(size_t)(r0 + r) * C + c0 + c];
    }
    __syncthreads();
    #pragma unroll
    for (int i = 0; i < 16; ++i) {
        int idx = tid + 256 * i;
        int ro = idx >> 6, co = idx & 63;
        out[(size_t)(c0 + ro) * R + r0 + co] = (f16)t[ro][co];
    }
}

// ---------------------------------------------------------------------------
// MFMA GEMM core (verbatim from R10, modes 0/1 only used):
// C(f32,opt)/C2(f16,opt) = A @ Bt^T + bias(LOCAL col index).
// BM=64, BN=128, BK=64, 256 thr = 4 waves, double-buffered LDS (48 KB).
//   mode 0: f16 source via global_load_lds (inverse-swizzled src, linear LDS)
//   mode 1: f32 row-major source; reg-staged cast, XOR-swizzled LDS writes.
// LDS[row][slot s] = elem[row][chunk s ^ (row&7)], chunk = 8 f16.
// ---------------------------------------------------------------------------
template<int BM, int BN, int AMODE, int BMODE>
__device__ __forceinline__ void gemm_core(
    const f16* __restrict__ Ah, const float* __restrict__ Af,
    const f16* __restrict__ Bth, const float* __restrict__ Btf,
    const float* __restrict__ bias, float* __restrict__ C,
    f16* __restrict__ C2, int K, int ldc, int lda, int ldb,
    int bx, int by, f16* Al, f16* Bl)
{
    constexpr int MF   = BM / 16;
    constexpr int NF   = BN / 64;
    constexpr int ABUF = BM * 64;
    constexpr int BBUF = BN * 64;
    const int tid = threadIdx.x, lane = tid & 63, wid = tid >> 6;
    const size_t row0 = (size_t)by * BM;
    const size_t col0 = (size_t)bx * BN;
    const int lrow = lane >> 3;
    const int lcs  = (lane & 7) ^ lrow;
    const int r15 = lane & 15, l4 = lane >> 4;
    const int crow = tid >> 2, ckc = tid & 3;

    f32x4 acc[MF][NF];
    #pragma unroll
    for (int m = 0; m < MF; ++m)
        #pragma unroll
        for (int n = 0; n < NF; ++n) acc[m][n] = (f32x4){0.f, 0.f, 0.f, 0.f};

    float4 aregs[(AMODE != 0) ? (BM / 64) : 1][4];
    float4 bregs[(BMODE != 0) ? (BN / 64) : 1][4];

    auto LOAD_A = [&](int kt) {
        if constexpr (AMODE == 1) {
            #pragma unroll
            for (int g = 0; g < BM / 64; ++g) {
                const float* src = Af + (row0 + g * 64 + crow) * (size_t)lda
                                      + kt * 64 + ckc * 16;
                #pragma unroll
                for (int q = 0; q < 4; ++q) aregs[g][q] = *(const float4*)(src + q * 4);
            }
        }
    };
    auto LOAD_B = [&](int kt) {
        if constexpr (BMODE == 1) {
            #pragma unroll
            for (int g = 0; g < BN / 64; ++g) {
                const float* src = Btf + (col0 + g * 64 + crow) * (size_t)ldb
                                       + kt * 64 + ckc * 16;
                #pragma unroll
                for (int q = 0; q < 4; ++q) bregs[g][q] = *(const float4*)(src + q * 4);
            }
        }
    };
    auto WRITE_A = [&](int buf) {
        if constexpr (AMODE != 0) {
            #pragma unroll
            for (int g = 0; g < BM / 64; ++g) {
                const int row = g * 64 + crow;
                f16x8 h0 = { (f16)aregs[g][0].x, (f16)aregs[g][0].y,
                             (f16)aregs[g][0].z, (f16)aregs[g][0].w,
                             (f16)aregs[g][1].x, (f16)aregs[g][1].y,
                             (f16)aregs[g][1].z, (f16)aregs[g][1].w };
                f16x8 h1 = { (f16)aregs[g][2].x, (f16)aregs[g][2].y,
                             (f16)aregs[g][2].z, (f16)aregs[g][2].w,
                             (f16)aregs[g][3].x, (f16)aregs[g][3].y,
                             (f16)aregs[g][3].z, (f16)aregs[g][3].w };
                f16* base = Al + buf * ABUF + row * 64;
                *(f16x8*)(base + (((ckc * 2 + 0) ^ (row & 7)) * 8)) = h0;
                *(f16x8*)(base + (((ckc * 2 + 1) ^ (row & 7)) * 8)) = h1;
            }
        }
    };
    auto WRITE_B = [&](int buf) {
        if constexpr (BMODE != 0) {
            #pragma unroll
            for (int g = 0; g < BN / 64; ++g) {
                const int row = g * 64 + crow;
                f16x8 h0 = { (f16)bregs[g][0].x, (f16)bregs[g][0].y,
                             (f16)bregs[g][0].z, (f16)bregs[g][0].w,
                             (f16)bregs[g][1].x, (f16)bregs[g][1].y,
                             (f16)bregs[g][1].z, (f16)bregs[g][1].w };
                f16x8 h1 = { (f16)bregs[g][2].x, (f16)bregs[g][2].y,
                             (f16)bregs[g][2].z, (f16)bregs[g][2].w,
                             (f16)bregs[g][3].x, (f16)bregs[g][3].y,
                             (f16)bregs[g][3].z, (f16)bregs[g][3].w };
                f16* base = Bl + buf * BBUF + row * 64;
                *(f16x8*)(base + (((ckc * 2 + 0) ^ (row & 7)) * 8)) = h0;
                *(f16x8*)(base + (((ckc * 2 + 1) ^ (row & 7)) * 8)) = h1;
            }
        }
    };
    auto STAGE_A16 = [&](int buf, int kt) {
        if constexpr (AMODE == 0) {
            const f16* Ab = Ah + row0 * lda + (size_t)kt * 64;
            #pragma unroll
            for (int j = 0; j < BM / 32; ++j) {
                const int c = wid * (BM / 32) + j;
                llds16(Ab + (size_t)(c * 8 + lrow) * lda + lcs * 8,
                       Al + buf * ABUF + c * 512);
            }
        }
    };
    auto STAGE_B16 = [&](int buf, int kt) {
        if constexpr (BMODE == 0) {
            const f16* Bb = Bth + col0 * ldb + (size_t)kt * 64;
            #pragma unroll
            for (int j = 0; j < BN / 32; ++j) {
                const int c = wid * (BN / 32) + j;
                llds16(Bb + (size_t)(c * 8 + lrow) * ldb + lcs * 8,
                       Bl + buf * BBUF + c * 512);
            }
        }
    };

    LOAD_A(0); LOAD_B(0);
    STAGE_A16(0, 0); STAGE_B16(0, 0);
    WRITE_A(0); WRITE_B(0);
    __syncthreads();

    const int nk = K >> 6;
    int cur = 0;
    for (int kt = 0; kt < nk; ++kt) {
        const bool more = (kt + 1 < nk);
        if (more) {
            STAGE_A16(cur ^ 1, kt + 1);
            STAGE_B16(cur ^ 1, kt + 1);
            LOAD_A(kt + 1);
            LOAD_B(kt + 1);
        }
        #pragma unroll
        for (int kk = 0; kk < 2; ++kk) {
            f16x8 af[MF], bfr[NF];
            #pragma unroll
            for (int m = 0; m < MF; ++m) {
                const int rowA = m * 16 + r15;
                af[m] = *(const f16x8*)(Al + cur * ABUF + rowA * 64 +
                                        (((kk * 4 + l4) ^ (r15 & 7)) * 8));
            }
            #pragma unroll
            for (int n = 0; n < NF; ++n) {
                const int rowB = wid * (BN / 4) + n * 16 + r15;
                bfr[n] = *(const f16x8*)(Bl + cur * BBUF + rowB * 64 +
                                         (((kk * 4 + l4) ^ (r15 & 7)) * 8));
            }
            #pragma unroll
            for (int m = 0; m < MF; ++m)
                #pragma unroll
                for (int n = 0; n < NF; ++n)
                    acc[m][n] = __builtin_amdgcn_mfma_f32_16x16x32_f16(
                        af[m], bfr[n], acc[m][n], 0, 0, 0);
        }
        if (more) { WRITE_A(cur ^ 1); WRITE_B(cur ^ 1); }
        __syncthreads();
        cur ^= 1;
    }

    // C/D layout: col = lane&15, row = (lane>>4)*4 + j
    const int cr = l4, cc = r15;
    #pragma unroll
    for (int n = 0; n < NF; ++n) {
        const size_t col = col0 + wid * (BN / 4) + n * 16 + cc;
        const float bvv = bias ? bias[(int)(col - col0)] : 0.f;
        #pragma unroll
        for (int m = 0; m < MF; ++m) {
            #pragma unroll
            for (int j = 0; j < 4; ++j) {
                const size_t row = row0 + m * 16 + cr * 4 + j;
                const float v = acc[m][n][j] + bvv;
                if (C)  C[row * ldc + col] = v;
                if (C2) C2[row * ldc + col] = (f16)v;
            }
        }
    }
}

// ---------------------------------------------------------------------------
// L1 prepA: ONLY what the small GEMMs need. grid 456 x 256.
//   [0,128)    Wk^T  -> btcomb rows [0,1024)
//   [128,256)  Wv^T  -> btcomb rows [1024,2048)
//   [256,320)  W1m^T -> btcomb rows [2048,2560)
//   [320,448)  W1q^T -> W1q_t
//   [448,456)  bqh[j] = sum_k bq[k] * W1q[k][j]
// ---------------------------------------------------------------------------
__global__ __launch_bounds__(256) void prepA(
    const float* __restrict__ Wk, const float* __restrict__ Wv,
    const float* __restrict__ W1, const float* __restrict__ bq,
    f16* __restrict__ btcomb, f16* __restrict__ W1q_t,
    float* __restrict__ bqh)
{
    __shared__ __align__(16) char smem[49152];
    const int bid = blockIdx.x, tid = threadIdx.x;

    if (bid < 128) {
        tr_tile((float(*)[65])smem, Wk, btcomb, 512, 1024, bid);
    } else if (bid < 256) {
        tr_tile((float(*)[65])smem, Wv, btcomb + (size_t)1024 * 512, 512, 1024, bid - 128);
    } else if (bid < 320) {
        tr_tile((float(*)[65])smem, W1 + (size_t)1024 * 512,
                btcomb + (size_t)2048 * 512, 512, 512, bid - 256);
    } else if (bid < 448) {
        tr_tile((float(*)[65])smem, W1, W1q_t, 1024, 512, bid - 320);
    } else {
        // bqh[p*64 + j] = sum_k bq[k] * W1[k][p*64+j]
        const int p = bid - 448;
        const int jl = tid & 63, slab = tid >> 6;
        float part = 0.f;
        const int k0 = slab * 256;
        for (int k = k0; k < k0 + 256; ++k)
            part += bq[k] * W1[(size_t)k * 512 + p * 64 + jl];
        float* red = (float*)smem;
        red[slab * 64 + jl] = part;
        __syncthreads();
        if (tid < 64)
            bqh[p * 64 + tid] = red[tid] + red[64 + tid] + red[128 + tid] + red[192 + tid];
    }
}

// ---------------------------------------------------------------------------
// L2 prepB: small GEMMs FIRST (critical path), prep-bulk fills idle CUs.
// grid 1680 x 256.
//   [0,64)       wq1t = W1q_t @ Wq^T -> btbig rows [1024,1536)  (modes 0,1)
//   [64,144)     kvm  = mem @ [Wk|Wv|W1m]^T + [bk|bv|b1]        (modes 1,0)
//   [144,1168)   hs f32->f16
//   [1168,1424)  Wq^T -> btbig rows [0,1024)
//   [1424,1680)  Wo^T -> Wo_t
// ---------------------------------------------------------------------------
__global__ __launch_bounds__(256) void prepB(
    const float* __restrict__ hs, const float* __restrict__ mem,
    const float* __restrict__ Wq, const float* __restrict__ Wo,
    const f16* __restrict__ btcomb, const f16* __restrict__ W1q_t,
    const float* __restrict__ bk, const float* __restrict__ bv,
    const float* __restrict__ b1,
    f16* __restrict__ hs_f16, f16* __restrict__ btbig,
    f16* __restrict__ Wo_t, f16* __restrict__ kvm)
{
    __shared__ __align__(16) char smem[49152];
    const int bid = blockIdx.x, tid = threadIdx.x;

    if (bid < 64) {
        // wq1t[h][n] = sum_k' W1q_t[h][k'] * Wq[n][k']  -> btbig rows [1024,1536)
        gemm_core<64, 128, 0, 1>(
            W1q_t, nullptr, nullptr, Wq, nullptr, nullptr,
            btbig + (size_t)1024 * DM,
            DM, DM, DM, DM, bid % 8, bid / 8,
            (f16*)smem, (f16*)(smem + 16384));
    } else if (bid < 144) {
        const int i = bid - 64;             // 20 bx x 4 by
        const int bx = i % 20, by = i / 20;
        const float* bseg = (bx < 8)  ? (bk + bx * 128)
                          : (bx < 16) ? (bv + (bx * 128 - 1024))
                                      : (b1 + (bx * 128 - 2048));
        gemm_core<64, 128, 1, 0>(
            nullptr, mem, btcomb, nullptr, bseg, nullptr, kvm,
            MEMD, KVLD, MEMD, MEMD, bx, by,
            (f16*)smem, (f16*)(smem + 16384));
    } else if (bid < 1168) {
        cast8(hs, hs_f16, (bid - 144) * 256 + tid);
    } else if (bid < 1424) {
        tr_tile((float(*)[65])smem, Wq, btbig, 1024, 1024, bid - 1168);
    } else {
        tr_tile((float(*)[65])smem, Wo, Wo_t, 1024, 1024, bid - 1424);
    }
}

// ---------------------------------------------------------------------------
// L3: qcat GEMM (384) + VoT GEMM (32) + mpt (8). grid 424 x 256.
// Verbatim from R10 (passing).
// ---------------------------------------------------------------------------
__global__ __launch_bounds__(256) void midgemm(
    const f16* __restrict__ hs_f16, const f16* __restrict__ btbig,
    const float* __restrict__ bq, const float* __restrict__ bqh,
    f16* __restrict__ qcat, const f16* __restrict__ kvm,
    const f16* __restrict__ Wo_t, f16* __restrict__ VoT,
    f16* __restrict__ mpt)
{
    __shared__ __align__(16) char smem[49152];
    const int bid = blockIdx.x, tid = threadIdx.x;

    if (bid < 384) {
        const int bx = bid % 12, by = bid / 12;
        const float* bias = (bx < 8) ? (bq + bx * 128) : (bqh + (bx - 8) * 128);
        gemm_core<64, 128, 0, 0>(
            hs_f16, nullptr, btbig, nullptr, bias, nullptr, qcat,
            DM, QLD, DM, DM, bx, by,
            (f16*)smem, (f16*)(smem + 16384));
        return;
    }
    if (bid < 416) {
        // VoT = Wo_t @ values^T (values = kvm cols [1024,2048), +bv folded)
        const int i = bid - 384;
        gemm_core<64, 128, 0, 0>(
            Wo_t, nullptr, kvm + 1024, nullptr, nullptr, nullptr, VoT,
            DM, 256, DM, KVLD, i % 2, i / 2,
            (f16*)smem, (f16*)(smem + 16384));
        return;
    }
    // mpt: m_part rows (kvm cols 2048..2560) -> [b][256 h2][128 m][2]
    f16 (*t2)[136] = (f16(*)[136])smem;
    const f16* mpart = kvm + 2048;
    const int mb = bid - 416, b = mb >> 2, hc = mb & 3;
    #pragma unroll
    for (int k = 0; k < 8; ++k) {
        int idx = tid + 256 * k;
        int m = idx >> 4, hq = idx & 15;
        *(f16x8*)(&t2[m][hq * 8]) =
            *(const f16x8*)(mpart + (size_t)(b * 128 + m) * KVLD + hc * 128 + hq * 8);
    }
    __syncthreads();
    #pragma unroll
    for (int k = 0; k < 32; ++k) {
        int idx = tid + 256 * k;
        int h2l = idx >> 7, m = idx & 127;
        f16x2 v = { t2[m][h2l * 2], t2[m][h2l * 2 + 1] };
        *(f16x2*)(mpt + ((size_t)b * 256 + hc * 64 + h2l) * 256 + m * 2) = v;
    }
}

// ---------------------------------------------------------------------------
// L4: fused relevance + scores + softmax + P@Vo + bo -> out (f32).
// grid 256 x 256 (8 s-rows/block). Verbatim from R8/R10 (passing).
// ---------------------------------------------------------------------------
__global__ __launch_bounds__(256) void relattn(
    const f16* __restrict__ qcat,    // [2048][QLD]: queries | q_part
    const f16* __restrict__ kvm,     // [256][KVLD]: keys in cols [0,1024)
    const f16* __restrict__ VoT,     // [1024][256]
    const f16* __restrict__ mpt,     // [b][256 h2][128 m][2]
    const float* __restrict__ W2,    // [512]
    const float* __restrict__ b2,    // [1]
    const float* __restrict__ bo,    // [1024]
    float* __restrict__ out,         // [2048][1024] f32
    float* __restrict__ attn_w)      // [2048][128]
{
    __shared__ __align__(16) char u[41984];      // qs|mps|w2s  then  sc
    __shared__ float rel_s[1024];                // [8][128] persistent
    __shared__ f16 Ps[8 * 136];

    const int tid = threadIdx.x;
    const int b = blockIdx.x >> 7, st = blockIdx.x & 127;
    const size_t rowbase = (size_t)b * SEQ + st * 8;
    const int w = tid >> 6, lane = tid & 63;
    const int l15 = lane & 15, l4 = lane >> 4;

    // ---------------- Phase R: relevance -> rel_s ----------------
    {
        f16* qs  = (f16*)u;                 // [8][512]  8 KB
        f16* mps = (f16*)(u + 8192);        // [64][256] 32 KB
        f16* w2s = (f16*)(u + 40960);       // [512]     1 KB

        {
            int r = tid >> 5, c = tid & 31;
            const f16* src = qcat + (rowbase + r) * QLD + 1024 + c * 16;
            *(f16x8*)(qs + r * 512 + c * 16)     = *(const f16x8*)(src);
            *(f16x8*)(qs + r * 512 + c * 16 + 8) = *(const f16x8*)(src + 8);
        }
        if (tid < 128) {
            float4 w4 = *(const float4*)(W2 + tid * 4);
            f16x4 hv = { (f16)w4.x, (f16)w4.y, (f16)w4.z, (f16)w4.w };
            *(f16x4*)(w2s + tid * 4) = hv;
        }
        const float b2v = b2[0];
        const int sg = w;

        float acc00 = 0.f, acc01 = 0.f, acc10 = 0.f, acc11 = 0.f;
        const f16* mptb = mpt + (size_t)b * 65536;

        for (int hc = 0; hc < 4; ++hc) {
            __syncthreads();
            {
                const f16x8* src = (const f16x8*)(mptb + hc * 16384);
                f16x8* dst = (f16x8*)mps;
                #pragma unroll
                for (int k = 0; k < 8; ++k) dst[tid + 256 * k] = src[tid + 256 * k];
            }
            __syncthreads();

            #pragma unroll 4
            for (int step = 0; step < 16; ++step) {
                const int habs = hc * 128 + step * 8;
                uint4 q0u = *(const uint4*)(qs + (2 * sg) * 512 + habs);
                uint4 q1u = *(const uint4*)(qs + (2 * sg + 1) * 512 + habs);
                uint4 wu  = *(const uint4*)(w2s + habs);
                const unsigned* q0p = (const unsigned*)&q0u;
                const unsigned* q1p = (const unsigned*)&q1u;
                const unsigned* wp_ = (const unsigned*)&wu;
                #pragma unroll
                for (int jj = 0; jj < 4; ++jj) {
                    uint2 mpu = *(const uint2*)(mps + ((step * 4 + jj) * 128 + 2 * lane) * 2);
                    f16x2 m0 = __builtin_bit_cast(f16x2, mpu.x);
                    f16x2 m1 = __builtin_bit_cast(f16x2, mpu.y);
                    f16x2 wp = __builtin_bit_cast(f16x2, wp_[jj]);
                    f16x2 q0 = __builtin_bit_cast(f16x2, q0p[jj]);
                    f16x2 q1 = __builtin_bit_cast(f16x2, q1p[jj]);
                    acc00 = dot2acc(relu2(q0 + m0), wp, acc00);
                    acc01 = dot2acc(relu2(q0 + m1), wp, acc01);
                    acc10 = dot2acc(relu2(q1 + m0), wp, acc10);
                    acc11 = dot2acc(relu2(q1 + m1), wp, acc11);
                }
            }
        }

        rel_s[(2 * sg) * 128 + 2 * lane]         = 1.f / (1.f + __expf(-(acc00 + b2v)));
        rel_s[(2 * sg) * 128 + 2 * lane + 1]     = 1.f / (1.f + __expf(-(acc01 + b2v)));
        rel_s[(2 * sg + 1) * 128 + 2 * lane]     = 1.f / (1.f + __expf(-(acc10 + b2v)));
        rel_s[(2 * sg + 1) * 128 + 2 * lane + 1] = 1.f / (1.f + __expf(-(acc11 + b2v)));
    }
    __syncthreads();   // rel_s ready; qs/mps dead -> sc may overwrite

    float* sc = (float*)u;   // [4][16][128] 32 KB

    // ---------------- Phase S: QK^T partials over k-quarter ----------------
    {
        f32x4 aq[8];
        #pragma unroll
        for (int n = 0; n < 8; ++n) aq[n] = (f32x4){0.f, 0.f, 0.f, 0.f};
        #pragma unroll
        for (int k4 = 0; k4 < 8; ++k4) {
            const int k0 = w * 256 + k4 * 32 + l4 * 8;
            f16x8 af = *(const f16x8*)(qcat + (rowbase + (l15 & 7)) * QLD + k0);
            #pragma unroll
            for (int n = 0; n < 8; ++n) {
                f16x8 bf = *(const f16x8*)(kvm + (size_t)(b * 128 + n * 16 + l15) * KVLD + k0);
                aq[n] = __builtin_amdgcn_mfma_f32_16x16x32_f16(af, bf, aq[n], 0, 0, 0);
            }
        }
        #pragma unroll
        for (int n = 0; n < 8; ++n)
            #pragma unroll
            for (int j = 0; j < 4; ++j)
                sc[(w * 16 + l4 * 4 + j) * 128 + n * 16 + l15] = aq[n][j];
    }
    __syncthreads();

    // ---------------- reduce partials, *rel/32, softmax ----------------
    {
        const int r = tid >> 5, seg = tid & 31;
        float4 xs = {0.f, 0.f, 0.f, 0.f};
        #pragma unroll
        for (int ww = 0; ww < 4; ++ww) {
            float4 p = *(const float4*)(sc + (ww * 16 + r) * 128 + seg * 4);
            xs.x += p.x; xs.y += p.y; xs.z += p.z; xs.w += p.w;
        }
        float4 rl = *(const float4*)(rel_s + r * 128 + seg * 4);
        float x[4];
        x[0] = xs.x * 0.03125f * rl.x; x[1] = xs.y * 0.03125f * rl.y;
        x[2] = xs.z * 0.03125f * rl.z; x[3] = xs.w * 0.03125f * rl.w;
        float mx = fmaxf(fmaxf(x[0], x[1]), fmaxf(x[2], x[3]));
        #pragma unroll
        for (int d = 1; d < 32; d <<= 1) mx = fmaxf(mx, __shfl_xor(mx, d));
        float ss = 0.f;
        #pragma unroll
        for (int c = 0; c < 4; ++c) { x[c] = __expf(x[c] - mx); ss += x[c]; }
        #pragma unroll
        for (int d = 1; d < 32; d <<= 1) ss += __shfl_xor(ss, d);
        const float inv = 1.f / ss;
        #pragma unroll
        for (int c = 0; c < 4; ++c) x[c] *= inv;
        float4 o = { x[0], x[1], x[2], x[3] };
        *(float4*)(attn_w + (rowbase + r) * 128 + seg * 4) = o;
        f16x4 ph = { (f16)x[0], (f16)x[1], (f16)x[2], (f16)x[3] };
        *(f16x4*)(Ps + r * 136 + seg * 4) = ph;
    }
    __syncthreads();

    // ---------------- Phase P: out = P @ Vo + bo over d-quarter ----------------
    {
        f16x8 pa[4];
        #pragma unroll
        for (int k = 0; k < 4; ++k)
            pa[k] = *(const f16x8*)(Ps + (l15 & 7) * 136 + k * 32 + l4 * 8);
        #pragma unroll
        for (int n2 = 0; n2 < 16; ++n2) {
            f32x4 ac = (f32x4){0.f, 0.f, 0.f, 0.f};
            const int d0 = w * 256 + n2 * 16;
            #pragma unroll
            for (int k = 0; k < 4; ++k) {
                f16x8 bf = *(const f16x8*)(VoT + (size_t)(d0 + l15) * 256 + b * 128 + k * 32 + l4 * 8);
                ac = __builtin_amdgcn_mfma_f32_16x16x32_f16(pa[k], bf, ac, 0, 0, 0);
            }
            if (l4 < 2) {
                const float bov = bo[d0 + l15];
                #pragma unroll
                for (int j = 0; j < 4; ++j)
                    out[(rowbase + l4 * 4 + j) * 1024 + d0 + l15] = ac[j] + bov;
            }
        }
    }
}

// ---------------------------------------------------------------------------
extern "C" void kernel_launch(void* const* d_in, const int* in_sizes, int n_in,
                              void* d_out, int out_size, void* d_ws, size_t ws_size,
                              hipStream_t stream)
{
    const float* hs  = (const float*)d_in[0];
    const float* mem = (const float*)d_in[1];
    const float* Wq  = (const float*)d_in[2];
    const float* bq  = (const float*)d_in[3];
    const float* Wk  = (const float*)d_in[4];
    const float* bk  = (const float*)d_in[5];
    const float* Wv  = (const float*)d_in[6];
    const float* bv  = (const float*)d_in[7];
    const float* Wo  = (const float*)d_in[8];
    const float* bo  = (const float*)d_in[9];
    const float* W1  = (const float*)d_in[10];  // (1536,512)
    const float* b1  = (const float*)d_in[11];
    const float* W2  = (const float*)d_in[12];
    const float* b2  = (const float*)d_in[13];

    float* out   = (float*)d_out;                       // (2,1024,1024)
    float* attnw = out + (size_t)BATCH * SEQ * DM;      // (2,1024,128)

    // workspace layout (16B-aligned, ~20.5 MB)
    char* wp = (char*)d_ws;
    f16* hs_f16 = (f16*)wp;  wp += (size_t)BATCH * SEQ * DM * 2;     // 4 MB
    f16* btbig  = (f16*)wp;  wp += (size_t)QLD * DM * 2;             // 3 MB
    f16* btcomb = (f16*)wp;  wp += (size_t)KVLD * MEMD * 2;          // 2.5 MB
    f16* Wo_t   = (f16*)wp;  wp += (size_t)DM * DM * 2;              // 2 MB
    f16* W1q_t  = (f16*)wp;  wp += (size_t)RELH * DM * 2;            // 1 MB
    f16* qcat   = (f16*)wp;  wp += (size_t)BATCH * SEQ * QLD * 2;    // 6 MB
    f16* kvm    = (f16*)wp;  wp += (size_t)BATCH * MMEM * KVLD * 2;  // 1.25 MB
    f16* VoT    = (f16*)wp;  wp += (size_t)DM * BATCH * MMEM * 2;    // 0.5 MB
    f16* mpt    = (f16*)wp;  wp += (size_t)BATCH * MMEM * RELH * 2;  // 0.25 MB
    float* bqh  = (float*)wp; wp += (size_t)RELH * 4;                // 2 KB

    dim3 blk(256);

    // L1: small-GEMM inputs only (btcomb, W1q_t, bqh)
    prepA<<<dim3(456), blk, 0, stream>>>(Wk, Wv, W1, bq, btcomb, W1q_t, bqh);

    // L2: wq1t + kvm GEMMs (front) overlapped with hs cast + Wq^T/Wo^T
    prepB<<<dim3(1680), blk, 0, stream>>>(
        hs, mem, Wq, Wo, btcomb, W1q_t, bk, bv, b1,
        hs_f16, btbig, Wo_t, kvm);

    // L3: qcat GEMM + VoT GEMM + mpt
    midgemm<<<dim3(424), blk, 0, stream>>>(
        hs_f16, btbig, bq, bqh, qcat, kvm, Wo_t, VoT, mpt);

    // L4: fused relevance + attention -> out, attn_w
    relattn<<<dim3(256), blk, 0, stream>>>(
        qcat, kvm, VoT, mpt, W2, b2, bo, out, attnw);
}

// Round 12
// 73.861 us; speedup vs baseline: 1.4919x; 1.3994x over previous
//
#include <hip/hip_runtime.h>
#include <math.h>

// Problem constants (fixed by reference)
#define BATCH 2
#define SEQ   1024
#define DM    1024   // D_MODEL
#define MMEM  128    // memory slots
#define MEMD  512    // MEM_DIM
#define RELH  512    // REL_HID
#define KVLD  2560   // ld of combined [keys|values|m_part]
#define QLD   1536   // ld of combined [queries|q_part]

typedef _Float16 f16;
typedef __attribute__((ext_vector_type(2))) _Float16 f16x2;
typedef __attribute__((ext_vector_type(4))) _Float16 f16x4;
typedef __attribute__((ext_vector_type(8))) _Float16 f16x8;
typedef __attribute__((ext_vector_type(4))) float    f32x4;

__device__ inline float dot2acc(f16x2 a, f16x2 b, float c) {
#if __has_builtin(__builtin_amdgcn_fdot2)
    return __builtin_amdgcn_fdot2(a, b, c, false);
#else
    return c + (float)a[0] * (float)b[0] + (float)a[1] * (float)b[1];
#endif
}
__device__ inline f16x2 relu2(f16x2 a) {
    f16x2 z = { (_Float16)0.0f, (_Float16)0.0f };
#if __has_builtin(__builtin_elementwise_max)
    return __builtin_elementwise_max(a, z);
#else
    f16x2 r;
    r[0] = a[0] > z[0] ? a[0] : z[0];
    r[1] = a[1] > z[1] ? a[1] : z[1];
    return r;
#endif
}

// async global->LDS, 16B per lane (wave-uniform LDS base + lane*16)
__device__ inline void llds16(const void* gp, void* lp) {
    __builtin_amdgcn_global_load_lds(
        (const __attribute__((address_space(1))) void*)gp,
        (__attribute__((address_space(3))) void*)lp,
        16, 0, 0);
}

__device__ inline void cast8(const float* __restrict__ in, f16* __restrict__ out, int i) {
    const float4* p = (const float4*)in + (size_t)i * 2;
    float4 a = p[0], b = p[1];
    f16x8 v = { (f16)a.x, (f16)a.y, (f16)a.z, (f16)a.w,
                (f16)b.x, (f16)b.y, (f16)b.z, (f16)b.w };
    *(f16x8*)(out + (size_t)i * 8) = v;
}

__device__ inline void tr_tile(float (*t)[65], const float* __restrict__ in,
                               f16* __restrict__ out, int R, int C, int tile) {
    const int tid = threadIdx.x;
    const int ctiles = C >> 6;
    const int r0 = (tile / ctiles) * 64, c0 = (tile % ctiles) * 64;
    #pragma unroll
    for (int i = 0; i < 16; ++i) {
        int idx = tid + 256 * i;
        int r = idx >> 6, c = idx & 63;
        t[c][r] = in[(size_t)(r0 + r) * C + c0 + c];
    }
    __syncthreads();
    #pragma unroll
    for (int i = 0; i < 16; ++i) {
        int idx = tid + 256 * i;
        int ro = idx >> 6, co = idx & 63;
        out[(size_t)(c0 + ro) * R + r0 + co] = (f16)t[ro][co];
    }
}

// ---------------------------------------------------------------------------
// MFMA GEMM core (R8-proven fast path only: f16 A/B via global_load_lds).
// C(f32,opt)/C2(f16,opt) = A @ Bt^T + bias(LOCAL col index).
// BM=64, BN=128, BK=64, 256 thr = 4 waves, double-buffered LDS (48 KB).
// Inverse-swizzled global source, linear LDS dest, XOR-swizzled frag reads.
// ---------------------------------------------------------------------------
__device__ __forceinline__ void gemm_core(
    const f16* __restrict__ A, const f16* __restrict__ Bt,
    const float* __restrict__ bias, float* __restrict__ C,
    f16* __restrict__ C2, int K, int ldc, int lda, int ldb,
    int bx, int by, f16* Al, f16* Bl)
{
    constexpr int BM = 64, BN = 128;
    constexpr int MF = BM / 16, NF = BN / 64;
    constexpr int ABUF = BM * 64, BBUF = BN * 64;
    const int tid = threadIdx.x, lane = tid & 63, wid = tid >> 6;
    const size_t row0 = (size_t)by * BM;
    const size_t col0 = (size_t)bx * BN;
    const int lrow = lane >> 3;
    const int lcs  = (lane & 7) ^ lrow;
    const int r15 = lane & 15, l4 = lane >> 4;

    f32x4 acc[MF][NF];
    #pragma unroll
    for (int m = 0; m < MF; ++m)
        #pragma unroll
        for (int n = 0; n < NF; ++n) acc[m][n] = (f32x4){0.f, 0.f, 0.f, 0.f};

    auto STAGE = [&](int buf, int kt) {
        const f16* Ab = A + row0 * lda + (size_t)kt * 64;
        const f16* Bb = Bt + col0 * ldb + (size_t)kt * 64;
        #pragma unroll
        for (int j = 0; j < BM / 32; ++j) {
            const int c = wid * (BM / 32) + j;
            llds16(Ab + (size_t)(c * 8 + lrow) * lda + lcs * 8,
                   Al + buf * ABUF + c * 512);
        }
        #pragma unroll
        for (int j = 0; j < BN / 32; ++j) {
            const int c = wid * (BN / 32) + j;
            llds16(Bb + (size_t)(c * 8 + lrow) * ldb + lcs * 8,
                   Bl + buf * BBUF + c * 512);
        }
    };

    STAGE(0, 0);
    __syncthreads();

    const int nk = K >> 6;
    int cur = 0;
    for (int kt = 0; kt < nk; ++kt) {
        if (kt + 1 < nk) STAGE(cur ^ 1, kt + 1);
        #pragma unroll
        for (int kk = 0; kk < 2; ++kk) {
            f16x8 af[MF], bfr[NF];
            #pragma unroll
            for (int m = 0; m < MF; ++m) {
                const int rowA = m * 16 + r15;
                af[m] = *(const f16x8*)(Al + cur * ABUF + rowA * 64 +
                                        (((kk * 4 + l4) ^ (r15 & 7)) * 8));
            }
            #pragma unroll
            for (int n = 0; n < NF; ++n) {
                const int rowB = wid * (BN / 4) + n * 16 + r15;
                bfr[n] = *(const f16x8*)(Bl + cur * BBUF + rowB * 64 +
                                         (((kk * 4 + l4) ^ (r15 & 7)) * 8));
            }
            #pragma unroll
            for (int m = 0; m < MF; ++m)
                #pragma unroll
                for (int n = 0; n < NF; ++n)
                    acc[m][n] = __builtin_amdgcn_mfma_f32_16x16x32_f16(
                        af[m], bfr[n], acc[m][n], 0, 0, 0);
        }
        __syncthreads();
        cur ^= 1;
    }

    // C/D layout: col = lane&15, row = (lane>>4)*4 + j
    const int cr = l4, cc = r15;
    #pragma unroll
    for (int n = 0; n < NF; ++n) {
        const size_t col = col0 + wid * (BN / 4) + n * 16 + cc;
        const float bvv = bias ? bias[(int)(col - col0)] : 0.f;
        #pragma unroll
        for (int m = 0; m < MF; ++m) {
            #pragma unroll
            for (int j = 0; j < 4; ++j) {
                const size_t row = row0 + m * 16 + cr * 4 + j;
                const float v = acc[m][n][j] + bvv;
                if (C)  C[row * ldc + col] = v;
                if (C2) C2[row * ldc + col] = (f16)v;
            }
        }
    }
}

// ---------------------------------------------------------------------------
// L1 prep: all casts + weight transposes. grid 2048 x 256.
//   [0,1024)     hs f32->f16
//   [1024,1088)  mem f32->f16
//   [1088,1344)  Wq^T  -> Wq_t
//   [1344,1600)  Wo^T  -> Wo_t
//   [1600,1728)  Wk^T  -> btcomb rows [0,1024)
//   [1728,1856)  Wv^T  -> btcomb rows [1024,2048)
//   [1856,1920)  W1m^T -> btcomb rows [2048,2560)
//   [1920,2048)  W1q^T -> W1q_t
// ---------------------------------------------------------------------------
__global__ __launch_bounds__(256) void prep(
    const float* __restrict__ hs, const float* __restrict__ mem,
    const float* __restrict__ Wq, const float* __restrict__ Wo,
    const float* __restrict__ Wk, const float* __restrict__ Wv,
    const float* __restrict__ W1,
    f16* __restrict__ hs_f16, f16* __restrict__ mem_f16,
    f16* __restrict__ Wq_t, f16* __restrict__ Wo_t,
    f16* __restrict__ btcomb, f16* __restrict__ W1q_t)
{
    __shared__ float t[64][65];
    const int bid = blockIdx.x, tid = threadIdx.x;

    if (bid < 1024) {
        cast8(hs, hs_f16, bid * 256 + tid);
    } else if (bid < 1088) {
        cast8(mem, mem_f16, (bid - 1024) * 256 + tid);
    } else if (bid < 1344) {
        tr_tile(t, Wq, Wq_t, 1024, 1024, bid - 1088);
    } else if (bid < 1600) {
        tr_tile(t, Wo, Wo_t, 1024, 1024, bid - 1344);
    } else if (bid < 1728) {
        tr_tile(t, Wk, btcomb, 512, 1024, bid - 1600);
    } else if (bid < 1856) {
        tr_tile(t, Wv, btcomb + (size_t)1024 * 512, 512, 1024, bid - 1728);
    } else if (bid < 1920) {
        tr_tile(t, W1 + (size_t)1024 * 512, btcomb + (size_t)2048 * 512,
                512, 512, bid - 1856);
    } else {
        tr_tile(t, W1, W1q_t, 1024, 512, bid - 1920);
    }
}

// ---------------------------------------------------------------------------
// L2 gemmA: queries (256 tiles) + kvm (80 tiles). grid 336 x 256.
//   queries: qcat cols [0,1024) = hs_f16 @ Wq_t^T + bq
//   kvm:     [keys|values+bv|m_part+b1] = mem_f16 @ btcomb^T + [bk|bv|b1]
// ---------------------------------------------------------------------------
__global__ __launch_bounds__(256) void gemmA(
    const f16* __restrict__ hs_f16, const f16* __restrict__ Wq_t,
    const float* __restrict__ bq, f16* __restrict__ qcat,
    const f16* __restrict__ mem_f16, const f16* __restrict__ btcomb,
    const float* __restrict__ bk, const float* __restrict__ bv,
    const float* __restrict__ b1, f16* __restrict__ kvm)
{
    __shared__ __align__(16) char smem[49152];
    f16* Al = (f16*)smem;
    f16* Bl = (f16*)(smem + 16384);
    const int bid = blockIdx.x;

    if (bid < 256) {
        const int bx = bid & 7, by = bid >> 3;
        gemm_core(hs_f16, Wq_t, bq + bx * 128, nullptr, qcat,
                  DM, QLD, DM, DM, bx, by, Al, Bl);
    } else {
        const int i = bid - 256;            // 20 bx x 4 by
        const int bx = i % 20, by = i / 20;
        const float* bseg = (bx < 8)  ? (bk + bx * 128)
                          : (bx < 16) ? (bv + (bx * 128 - 1024))
                                      : (b1 + (bx * 128 - 2048));
        gemm_core(mem_f16, btcomb, bseg, nullptr, kvm,
                  MEMD, KVLD, MEMD, MEMD, bx, by, Al, Bl);
    }
}

// ---------------------------------------------------------------------------
// L3 gemmB: q_part (128 tiles) + VoT (32) + mpt (8). grid 168 x 256.
//   q_part: qcat cols [1024,1536) = qcat cols[0,1024) @ W1q_t^T (no bias;
//           bq already inside queries)
//   VoT:    Wo_t @ values^T (values = kvm cols [1024,2048), +bv folded)
// ---------------------------------------------------------------------------
__global__ __launch_bounds__(256) void gemmB(
    const f16* __restrict__ qcat_in, f16* __restrict__ qcat,
    const f16* __restrict__ W1q_t, const f16* __restrict__ kvm,
    const f16* __restrict__ Wo_t, f16* __restrict__ VoT,
    f16* __restrict__ mpt)
{
    __shared__ __align__(16) char smem[49152];
    f16* Al = (f16*)smem;
    f16* Bl = (f16*)(smem + 16384);
    const int bid = blockIdx.x, tid = threadIdx.x;

    if (bid < 128) {
        const int bx = bid & 3, by = bid >> 2;
        gemm_core(qcat_in, W1q_t, nullptr, nullptr, qcat + 1024,
                  DM, QLD, QLD, DM, bx, by, Al, Bl);
        return;
    }
    if (bid < 160) {
        const int i = bid - 128;
        gemm_core(Wo_t, kvm + 1024, nullptr, nullptr, VoT,
                  DM, 256, DM, KVLD, i % 2, i / 2, Al, Bl);
        return;
    }
    // mpt: m_part rows (kvm cols 2048..2560) -> [b][256 h2][128 m][2]
    f16 (*t2)[136] = (f16(*)[136])smem;
    const f16* mpart = kvm + 2048;
    const int mb = bid - 160, b = mb >> 2, hc = mb & 3;
    #pragma unroll
    for (int k = 0; k < 8; ++k) {
        int idx = tid + 256 * k;
        int m = idx >> 4, hq = idx & 15;
        *(f16x8*)(&t2[m][hq * 8]) =
            *(const f16x8*)(mpart + (size_t)(b * 128 + m) * KVLD + hc * 128 + hq * 8);
    }
    __syncthreads();
    #pragma unroll
    for (int k = 0; k < 32; ++k) {
        int idx = tid + 256 * k;
        int h2l = idx >> 7, m = idx & 127;
        f16x2 v = { t2[m][h2l * 2], t2[m][h2l * 2 + 1] };
        *(f16x2*)(mpt + ((size_t)b * 256 + hc * 64 + h2l) * 256 + m * 2) = v;
    }
}

// ---------------------------------------------------------------------------
// L4: fused relevance + scores + softmax + P@Vo + bo -> out (f32).
// grid 256 x 256 (8 s-rows/block). Verbatim from R8 (passing).
// ---------------------------------------------------------------------------
__global__ __launch_bounds__(256) void relattn(
    const f16* __restrict__ qcat,    // [2048][QLD]: queries | q_part
    const f16* __restrict__ kvm,     // [256][KVLD]: keys in cols [0,1024)
    const f16* __restrict__ VoT,     // [1024][256]
    const f16* __restrict__ mpt,     // [b][256 h2][128 m][2]
    const float* __restrict__ W2,    // [512]
    const float* __restrict__ b2,    // [1]
    const float* __restrict__ bo,    // [1024]
    float* __restrict__ out,         // [2048][1024] f32
    float* __restrict__ attn_w)      // [2048][128]
{
    __shared__ __align__(16) char u[41984];      // qs|mps|w2s  then  sc
    __shared__ float rel_s[1024];                // [8][128] persistent
    __shared__ f16 Ps[8 * 136];

    const int tid = threadIdx.x;
    const int b = blockIdx.x >> 7, st = blockIdx.x & 127;
    const size_t rowbase = (size_t)b * SEQ + st * 8;
    const int w = tid >> 6, lane = tid & 63;
    const int l15 = lane & 15, l4 = lane >> 4;

    // ---------------- Phase R: relevance -> rel_s ----------------
    {
        f16* qs  = (f16*)u;                 // [8][512]  8 KB
        f16* mps = (f16*)(u + 8192);        // [64][256] 32 KB
        f16* w2s = (f16*)(u + 40960);       // [512]     1 KB

        {
            int r = tid >> 5, c = tid & 31;
            const f16* src = qcat + (rowbase + r) * QLD + 1024 + c * 16;
            *(f16x8*)(qs + r * 512 + c * 16)     = *(const f16x8*)(src);
            *(f16x8*)(qs + r * 512 + c * 16 + 8) = *(const f16x8*)(src + 8);
        }
        if (tid < 128) {
            float4 w4 = *(const float4*)(W2 + tid * 4);
            f16x4 hv = { (f16)w4.x, (f16)w4.y, (f16)w4.z, (f16)w4.w };
            *(f16x4*)(w2s + tid * 4) = hv;
        }
        const float b2v = b2[0];
        const int sg = w;

        float acc00 = 0.f, acc01 = 0.f, acc10 = 0.f, acc11 = 0.f;
        const f16* mptb = mpt + (size_t)b * 65536;

        for (int hc = 0; hc < 4; ++hc) {
            __syncthreads();
            {
                const f16x8* src = (const f16x8*)(mptb + hc * 16384);
                f16x8* dst = (f16x8*)mps;
                #pragma unroll
                for (int k = 0; k < 8; ++k) dst[tid + 256 * k] = src[tid + 256 * k];
            }
            __syncthreads();

            #pragma unroll 4
            for (int step = 0; step < 16; ++step) {
                const int habs = hc * 128 + step * 8;
                uint4 q0u = *(const uint4*)(qs + (2 * sg) * 512 + habs);
                uint4 q1u = *(const uint4*)(qs + (2 * sg + 1) * 512 + habs);
                uint4 wu  = *(const uint4*)(w2s + habs);
                const unsigned* q0p = (const unsigned*)&q0u;
                const unsigned* q1p = (const unsigned*)&q1u;
                const unsigned* wp_ = (const unsigned*)&wu;
                #pragma unroll
                for (int jj = 0; jj < 4; ++jj) {
                    uint2 mpu = *(const uint2*)(mps + ((step * 4 + jj) * 128 + 2 * lane) * 2);
                    f16x2 m0 = __builtin_bit_cast(f16x2, mpu.x);
                    f16x2 m1 = __builtin_bit_cast(f16x2, mpu.y);
                    f16x2 wp = __builtin_bit_cast(f16x2, wp_[jj]);
                    f16x2 q0 = __builtin_bit_cast(f16x2, q0p[jj]);
                    f16x2 q1 = __builtin_bit_cast(f16x2, q1p[jj]);
                    acc00 = dot2acc(relu2(q0 + m0), wp, acc00);
                    acc01 = dot2acc(relu2(q0 + m1), wp, acc01);
                    acc10 = dot2acc(relu2(q1 + m0), wp, acc10);
                    acc11 = dot2acc(relu2(q1 + m1), wp, acc11);
                }
            }
        }

        rel_s[(2 * sg) * 128 + 2 * lane]         = 1.f / (1.f + __expf(-(acc00 + b2v)));
        rel_s[(2 * sg) * 128 + 2 * lane + 1]     = 1.f / (1.f + __expf(-(acc01 + b2v)));
        rel_s[(2 * sg + 1) * 128 + 2 * lane]     = 1.f / (1.f + __expf(-(acc10 + b2v)));
        rel_s[(2 * sg + 1) * 128 + 2 * lane + 1] = 1.f / (1.f + __expf(-(acc11 + b2v)));
    }
    __syncthreads();   // rel_s ready; qs/mps dead -> sc may overwrite

    float* sc = (float*)u;   // [4][16][128] 32 KB

    // ---------------- Phase S: QK^T partials over k-quarter ----------------
    {
        f32x4 aq[8];
        #pragma unroll
        for (int n = 0; n < 8; ++n) aq[n] = (f32x4){0.f, 0.f, 0.f, 0.f};
        #pragma unroll
        for (int k4 = 0; k4 < 8; ++k4) {
            const int k0 = w * 256 + k4 * 32 + l4 * 8;
            f16x8 af = *(const f16x8*)(qcat + (rowbase + (l15 & 7)) * QLD + k0);
            #pragma unroll
            for (int n = 0; n < 8; ++n) {
                f16x8 bf = *(const f16x8*)(kvm + (size_t)(b * 128 + n * 16 + l15) * KVLD + k0);
                aq[n] = __builtin_amdgcn_mfma_f32_16x16x32_f16(af, bf, aq[n], 0, 0, 0);
            }
        }
        #pragma unroll
        for (int n = 0; n < 8; ++n)
            #pragma unroll
            for (int j = 0; j < 4; ++j)
                sc[(w * 16 + l4 * 4 + j) * 128 + n * 16 + l15] = aq[n][j];
    }
    __syncthreads();

    // ---------------- reduce partials, *rel/32, softmax ----------------
    {
        const int r = tid >> 5, seg = tid & 31;
        float4 xs = {0.f, 0.f, 0.f, 0.f};
        #pragma unroll
        for (int ww = 0; ww < 4; ++ww) {
            float4 p = *(const float4*)(sc + (ww * 16 + r) * 128 + seg * 4);
            xs.x += p.x; xs.y += p.y; xs.z += p.z; xs.w += p.w;
        }
        float4 rl = *(const float4*)(rel_s + r * 128 + seg * 4);
        float x[4];
        x[0] = xs.x * 0.03125f * rl.x; x[1] = xs.y * 0.03125f * rl.y;
        x[2] = xs.z * 0.03125f * rl.z; x[3] = xs.w * 0.03125f * rl.w;
        float mx = fmaxf(fmaxf(x[0], x[1]), fmaxf(x[2], x[3]));
        #pragma unroll
        for (int d = 1; d < 32; d <<= 1) mx = fmaxf(mx, __shfl_xor(mx, d));
        float ss = 0.f;
        #pragma unroll
        for (int c = 0; c < 4; ++c) { x[c] = __expf(x[c] - mx); ss += x[c]; }
        #pragma unroll
        for (int d = 1; d < 32; d <<= 1) ss += __shfl_xor(ss, d);
        const float inv = 1.f / ss;
        #pragma unroll
        for (int c = 0; c < 4; ++c) x[c] *= inv;
        float4 o = { x[0], x[1], x[2], x[3] };
        *(float4*)(attn_w + (rowbase + r) * 128 + seg * 4) = o;
        f16x4 ph = { (f16)x[0], (f16)x[1], (f16)x[2], (f16)x[3] };
        *(f16x4*)(Ps + r * 136 + seg * 4) = ph;
    }
    __syncthreads();

    // ---------------- Phase P: out = P @ Vo + bo over d-quarter ----------------
    {
        f16x8 pa[4];
        #pragma unroll
        for (int k = 0; k < 4; ++k)
            pa[k] = *(const f16x8*)(Ps + (l15 & 7) * 136 + k * 32 + l4 * 8);
        #pragma unroll
        for (int n2 = 0; n2 < 16; ++n2) {
            f32x4 ac = (f32x4){0.f, 0.f, 0.f, 0.f};
            const int d0 = w * 256 + n2 * 16;
            #pragma unroll
            for (int k = 0; k < 4; ++k) {
                f16x8 bf = *(const f16x8*)(VoT + (size_t)(d0 + l15) * 256 + b * 128 + k * 32 + l4 * 8);
                ac = __builtin_amdgcn_mfma_f32_16x16x32_f16(pa[k], bf, ac, 0, 0, 0);
            }
            if (l4 < 2) {
                const float bov = bo[d0 + l15];
                #pragma unroll
                for (int j = 0; j < 4; ++j)
                    out[(rowbase + l4 * 4 + j) * 1024 + d0 + l15] = ac[j] + bov;
            }
        }
    }
}

// ---------------------------------------------------------------------------
extern "C" void kernel_launch(void* const* d_in, const int* in_sizes, int n_in,
                              void* d_out, int out_size, void* d_ws, size_t ws_size,
                              hipStream_t stream)
{
    const float* hs  = (const float*)d_in[0];
    const float* mem = (const float*)d_in[1];
    const float* Wq  = (const float*)d_in[2];
    const float* bq  = (const float*)d_in[3];
    const float* Wk  = (const float*)d_in[4];
    const float* bk  = (const float*)d_in[5];
    const float* Wv  = (const float*)d_in[6];
    const float* bv  = (const float*)d_in[7];
    const float* Wo  = (const float*)d_in[8];
    const float* bo  = (const float*)d_in[9];
    const float* W1  = (const float*)d_in[10];  // (1536,512)
    const float* b1  = (const float*)d_in[11];
    const float* W2  = (const float*)d_in[12];
    const float* b2  = (const float*)d_in[13];

    float* out   = (float*)d_out;                       // (2,1024,1024)
    float* attnw = out + (size_t)BATCH * SEQ * DM;      // (2,1024,128)

    // workspace layout (16B-aligned, ~19.8 MB)
    char* wp = (char*)d_ws;
    f16* hs_f16  = (f16*)wp;  wp += (size_t)BATCH * SEQ * DM * 2;     // 4 MB
    f16* mem_f16 = (f16*)wp;  wp += (size_t)BATCH * MMEM * MEMD * 2;  // 0.25 MB
    f16* Wq_t    = (f16*)wp;  wp += (size_t)DM * DM * 2;              // 2 MB
    f16* Wo_t    = (f16*)wp;  wp += (size_t)DM * DM * 2;              // 2 MB
    f16* btcomb  = (f16*)wp;  wp += (size_t)KVLD * MEMD * 2;          // 2.5 MB
    f16* W1q_t   = (f16*)wp;  wp += (size_t)RELH * DM * 2;            // 1 MB
    f16* qcat    = (f16*)wp;  wp += (size_t)BATCH * SEQ * QLD * 2;    // 6 MB
    f16* kvm     = (f16*)wp;  wp += (size_t)BATCH * MMEM * KVLD * 2;  // 1.25 MB
    f16* VoT     = (f16*)wp;  wp += (size_t)DM * BATCH * MMEM * 2;    // 0.5 MB
    f16* mpt     = (f16*)wp;  wp += (size_t)BATCH * MMEM * RELH * 2;  // 0.25 MB

    dim3 blk(256);

    // L1: casts + weight transposes
    prep<<<dim3(2048), blk, 0, stream>>>(
        hs, mem, Wq, Wo, Wk, Wv, W1,
        hs_f16, mem_f16, Wq_t, Wo_t, btcomb, W1q_t);

    // L2: queries GEMM + kvm GEMM
    gemmA<<<dim3(336), blk, 0, stream>>>(
        hs_f16, Wq_t, bq, qcat, mem_f16, btcomb, bk, bv, b1, kvm);

    // L3: q_part GEMM + VoT GEMM + mpt
    gemmB<<<dim3(168), blk, 0, stream>>>(
        qcat, qcat, W1q_t, kvm, Wo_t, VoT, mpt);

    // L4: fused relevance + attention -> out, attn_w
    relattn<<<dim3(256), blk, 0, stream>>>(
        qcat, kvm, VoT, mpt, W2, b2, bo, out, attnw);
}

// Round 13
// 68.755 us; speedup vs baseline: 1.6027x; 1.0743x over previous
//
#include <hip/hip_runtime.h>
#include <math.h>

// Problem constants (fixed by reference)
#define BATCH 2
#define SEQ   1024
#define DM    1024   // D_MODEL
#define MMEM  128    // memory slots
#define MEMD  512    // MEM_DIM
#define RELH  512    // REL_HID
#define KVLD  2560   // ld of combined [keys|values|m_part]
#define QLD   1536   // ld of combined [queries|q_part]

typedef _Float16 f16;
typedef __attribute__((ext_vector_type(2))) _Float16 f16x2;
typedef __attribute__((ext_vector_type(4))) _Float16 f16x4;
typedef __attribute__((ext_vector_type(8))) _Float16 f16x8;
typedef __attribute__((ext_vector_type(4))) float    f32x4;

__device__ inline float dot2acc(f16x2 a, f16x2 b, float c) {
#if __has_builtin(__builtin_amdgcn_fdot2)
    return __builtin_amdgcn_fdot2(a, b, c, false);
#else
    return c + (float)a[0] * (float)b[0] + (float)a[1] * (float)b[1];
#endif
}
__device__ inline f16x2 relu2(f16x2 a) {
    f16x2 z = { (_Float16)0.0f, (_Float16)0.0f };
#if __has_builtin(__builtin_elementwise_max)
    return __builtin_elementwise_max(a, z);
#else
    f16x2 r;
    r[0] = a[0] > z[0] ? a[0] : z[0];
    r[1] = a[1] > z[1] ? a[1] : z[1];
    return r;
#endif
}

// async global->LDS, 16B per lane (wave-uniform LDS base + lane*16)
__device__ inline void llds16(const void* gp, void* lp) {
    __builtin_amdgcn_global_load_lds(
        (const __attribute__((address_space(1))) void*)gp,
        (__attribute__((address_space(3))) void*)lp,
        16, 0, 0);
}

__device__ inline void cast8(const float* __restrict__ in, f16* __restrict__ out, int i) {
    const float4* p = (const float4*)in + (size_t)i * 2;
    float4 a = p[0], b = p[1];
    f16x8 v = { (f16)a.x, (f16)a.y, (f16)a.z, (f16)a.w,
                (f16)b.x, (f16)b.y, (f16)b.z, (f16)b.w };
    *(f16x8*)(out + (size_t)i * 8) = v;
}

__device__ inline void tr_tile(float (*t)[65], const float* __restrict__ in,
                               f16* __restrict__ out, int R, int C, int tile) {
    const int tid = threadIdx.x;
    const int ctiles = C >> 6;
    const int r0 = (tile / ctiles) * 64, c0 = (tile % ctiles) * 64;
    #pragma unroll
    for (int i = 0; i < 16; ++i) {
        int idx = tid + 256 * i;
        int r = idx >> 6, c = idx & 63;
        t[c][r] = in[(size_t)(r0 + r) * C + c0 + c];
    }
    __syncthreads();
    #pragma unroll
    for (int i = 0; i < 16; ++i) {
        int idx = tid + 256 * i;
        int ro = idx >> 6, co = idx & 63;
        out[(size_t)(c0 + ro) * R + r0 + co] = (f16)t[ro][co];
    }
}

// ---------------------------------------------------------------------------
// MFMA GEMM core: f16 A/B via global_load_lds; 3-buffer depth-2 prefetch with
// COUNTED vmcnt (T4): per K-step, one stage (6 llds16/wave) stays in flight
// across the barrier; per-tile stall ~latency-2*iter instead of full latency.
// Schedule: [wait vmcnt(6) -> stage(kt) landed] -> s_barrier ->
//           issue STAGE(kt+2) into buf[(kt+2)%3] -> MFMA on buf[kt%3].
// Hazards: STAGE(kt+2) writes buf[(kt-1)%3]; all waves finished reading it
// before barrier(kt). Last tile waits vmcnt(0). asm "memory" clobbers keep
// the compiler from hoisting frag ds_reads above the waits/barrier.
// C(f32,opt)/C2(f16,opt) = A @ Bt^T + bias(LOCAL col index).
// BM=64, BN=128, BK=64, 256 thr = 4 waves. LDS: 3*(8+16) KB = 72 KB.
// ---------------------------------------------------------------------------
__device__ __forceinline__ void gemm_core(
    const f16* __restrict__ A, const f16* __restrict__ Bt,
    const float* __restrict__ bias, float* __restrict__ C,
    f16* __restrict__ C2, int K, int ldc, int lda, int ldb,
    int bx, int by, f16* Al, f16* Bl)
{
    constexpr int BM = 64, BN = 128;
    constexpr int MF = BM / 16, NF = BN / 64;
    constexpr int ABUF = BM * 64, BBUF = BN * 64;
    const int tid = threadIdx.x, lane = tid & 63, wid = tid >> 6;
    const size_t row0 = (size_t)by * BM;
    const size_t col0 = (size_t)bx * BN;
    const int lrow = lane >> 3;
    const int lcs  = (lane & 7) ^ lrow;
    const int r15 = lane & 15, l4 = lane >> 4;

    f32x4 acc[MF][NF];
    #pragma unroll
    for (int m = 0; m < MF; ++m)
        #pragma unroll
        for (int n = 0; n < NF; ++n) acc[m][n] = (f32x4){0.f, 0.f, 0.f, 0.f};

    auto STAGE = [&](int buf, int kt) {
        const f16* Ab = A + row0 * lda + (size_t)kt * 64;
        const f16* Bb = Bt + col0 * ldb + (size_t)kt * 64;
        #pragma unroll
        for (int j = 0; j < BM / 32; ++j) {
            const int c = wid * (BM / 32) + j;
            llds16(Ab + (size_t)(c * 8 + lrow) * lda + lcs * 8,
                   Al + buf * ABUF + c * 512);
        }
        #pragma unroll
        for (int j = 0; j < BN / 32; ++j) {
            const int c = wid * (BN / 32) + j;
            llds16(Bb + (size_t)(c * 8 + lrow) * ldb + lcs * 8,
                   Bl + buf * BBUF + c * 512);
        }
    };

    const int nk = K >> 6;   // all call sites: nk in {8, 16}
    STAGE(0, 0);
    STAGE(1, 1);

    int cur = 0, stg = 2;
    for (int kt = 0; kt < nk; ++kt) {
        // stage(kt) landed; stage(kt+1) (6 newest) may stay in flight
        if (kt + 1 < nk) asm volatile("s_waitcnt vmcnt(6)" ::: "memory");
        else             asm volatile("s_waitcnt vmcnt(0)" ::: "memory");
        asm volatile("s_barrier" ::: "memory");
        if (kt + 2 < nk) {
            STAGE(stg, kt + 2);
            stg = (stg == 2) ? 0 : stg + 1;
        }
        #pragma unroll
        for (int kk = 0; kk < 2; ++kk) {
            f16x8 af[MF], bfr[NF];
            #pragma unroll
            for (int m = 0; m < MF; ++m) {
                const int rowA = m * 16 + r15;
                af[m] = *(const f16x8*)(Al + cur * ABUF + rowA * 64 +
                                        (((kk * 4 + l4) ^ (r15 & 7)) * 8));
            }
            #pragma unroll
            for (int n = 0; n < NF; ++n) {
                const int rowB = wid * (BN / 4) + n * 16 + r15;
                bfr[n] = *(const f16x8*)(Bl + cur * BBUF + rowB * 64 +
                                         (((kk * 4 + l4) ^ (r15 & 7)) * 8));
            }
            #pragma unroll
            for (int m = 0; m < MF; ++m)
                #pragma unroll
                for (int n = 0; n < NF; ++n)
                    acc[m][n] = __builtin_amdgcn_mfma_f32_16x16x32_f16(
                        af[m], bfr[n], acc[m][n], 0, 0, 0);
        }
        cur = (cur == 2) ? 0 : cur + 1;
    }

    // C/D layout: col = lane&15, row = (lane>>4)*4 + j
    const int cr = l4, cc = r15;
    #pragma unroll
    for (int n = 0; n < NF; ++n) {
        const size_t col = col0 + wid * (BN / 4) + n * 16 + cc;
        const float bvv = bias ? bias[(int)(col - col0)] : 0.f;
        #pragma unroll
        for (int m = 0; m < MF; ++m) {
            #pragma unroll
            for (int j = 0; j < 4; ++j) {
                const size_t row = row0 + m * 16 + cr * 4 + j;
                const float v = acc[m][n][j] + bvv;
                if (C)  C[row * ldc + col] = v;
                if (C2) C2[row * ldc + col] = (f16)v;
            }
        }
    }
}

// ---------------------------------------------------------------------------
// L1 prep: all casts + weight transposes. grid 2048 x 256. (R12 verbatim)
// ---------------------------------------------------------------------------
__global__ __launch_bounds__(256) void prep(
    const float* __restrict__ hs, const float* __restrict__ mem,
    const float* __restrict__ Wq, const float* __restrict__ Wo,
    const float* __restrict__ Wk, const float* __restrict__ Wv,
    const float* __restrict__ W1,
    f16* __restrict__ hs_f16, f16* __restrict__ mem_f16,
    f16* __restrict__ Wq_t, f16* __restrict__ Wo_t,
    f16* __restrict__ btcomb, f16* __restrict__ W1q_t)
{
    __shared__ float t[64][65];
    const int bid = blockIdx.x, tid = threadIdx.x;

    if (bid < 1024) {
        cast8(hs, hs_f16, bid * 256 + tid);
    } else if (bid < 1088) {
        cast8(mem, mem_f16, (bid - 1024) * 256 + tid);
    } else if (bid < 1344) {
        tr_tile(t, Wq, Wq_t, 1024, 1024, bid - 1088);
    } else if (bid < 1600) {
        tr_tile(t, Wo, Wo_t, 1024, 1024, bid - 1344);
    } else if (bid < 1728) {
        tr_tile(t, Wk, btcomb, 512, 1024, bid - 1600);
    } else if (bid < 1856) {
        tr_tile(t, Wv, btcomb + (size_t)1024 * 512, 512, 1024, bid - 1728);
    } else if (bid < 1920) {
        tr_tile(t, W1 + (size_t)1024 * 512, btcomb + (size_t)2048 * 512,
                512, 512, bid - 1856);
    } else {
        tr_tile(t, W1, W1q_t, 1024, 512, bid - 1920);
    }
}

// ---------------------------------------------------------------------------
// L2 gemmA: queries (256 tiles) + kvm (80 tiles). grid 336 x 256.
// ---------------------------------------------------------------------------
__global__ __launch_bounds__(256) void gemmA(
    const f16* __restrict__ hs_f16, const f16* __restrict__ Wq_t,
    const float* __restrict__ bq, f16* __restrict__ qcat,
    const f16* __restrict__ mem_f16, const f16* __restrict__ btcomb,
    const float* __restrict__ bk, const float* __restrict__ bv,
    const float* __restrict__ b1, f16* __restrict__ kvm)
{
    __shared__ __align__(16) char smem[73728];   // Al 24 KB | Bl 48 KB
    f16* Al = (f16*)smem;
    f16* Bl = (f16*)(smem + 24576);
    const int bid = blockIdx.x;

    if (bid < 256) {
        const int bx = bid & 7, by = bid >> 3;
        gemm_core(hs_f16, Wq_t, bq + bx * 128, nullptr, qcat,
                  DM, QLD, DM, DM, bx, by, Al, Bl);
    } else {
        const int i = bid - 256;            // 20 bx x 4 by
        const int bx = i % 20, by = i / 20;
        const float* bseg = (bx < 8)  ? (bk + bx * 128)
                          : (bx < 16) ? (bv + (bx * 128 - 1024))
                                      : (b1 + (bx * 128 - 2048));
        gemm_core(mem_f16, btcomb, bseg, nullptr, kvm,
                  MEMD, KVLD, MEMD, MEMD, bx, by, Al, Bl);
    }
}

// ---------------------------------------------------------------------------
// L3 gemmB: q_part (128 tiles) + VoT (32) + mpt (8). grid 168 x 256.
// ---------------------------------------------------------------------------
__global__ __launch_bounds__(256) void gemmB(
    const f16* __restrict__ qcat_in, f16* __restrict__ qcat,
    const f16* __restrict__ W1q_t, const f16* __restrict__ kvm,
    const f16* __restrict__ Wo_t, f16* __restrict__ VoT,
    f16* __restrict__ mpt)
{
    __shared__ __align__(16) char smem[73728];
    f16* Al = (f16*)smem;
    f16* Bl = (f16*)(smem + 24576);
    const int bid = blockIdx.x, tid = threadIdx.x;

    if (bid < 128) {
        const int bx = bid & 3, by = bid >> 2;
        gemm_core(qcat_in, W1q_t, nullptr, nullptr, qcat + 1024,
                  DM, QLD, QLD, DM, bx, by, Al, Bl);
        return;
    }
    if (bid < 160) {
        const int i = bid - 128;
        gemm_core(Wo_t, kvm + 1024, nullptr, nullptr, VoT,
                  DM, 256, DM, KVLD, i % 2, i / 2, Al, Bl);
        return;
    }
    // mpt: m_part rows (kvm cols 2048..2560) -> [b][256 h2][128 m][2]
    f16 (*t2)[136] = (f16(*)[136])smem;
    const f16* mpart = kvm + 2048;
    const int mb = bid - 160, b = mb >> 2, hc = mb & 3;
    #pragma unroll
    for (int k = 0; k < 8; ++k) {
        int idx = tid + 256 * k;
        int m = idx >> 4, hq = idx & 15;
        *(f16x8*)(&t2[m][hq * 8]) =
            *(const f16x8*)(mpart + (size_t)(b * 128 + m) * KVLD + hc * 128 + hq * 8);
    }
    __syncthreads();
    #pragma unroll
    for (int k = 0; k < 32; ++k) {
        int idx = tid + 256 * k;
        int h2l = idx >> 7, m = idx & 127;
        f16x2 v = { t2[m][h2l * 2], t2[m][h2l * 2 + 1] };
        *(f16x2*)(mpt + ((size_t)b * 256 + hc * 64 + h2l) * 256 + m * 2) = v;
    }
}

// ---------------------------------------------------------------------------
// L4: fused relevance + scores + softmax + P@Vo + bo -> out (f32).
// grid 256 x 256 (8 s-rows/block). Verbatim from R8/R12 (passing).
// ---------------------------------------------------------------------------
__global__ __launch_bounds__(256) void relattn(
    const f16* __restrict__ qcat,    // [2048][QLD]: queries | q_part
    const f16* __restrict__ kvm,     // [256][KVLD]: keys in cols [0,1024)
    const f16* __restrict__ VoT,     // [1024][256]
    const f16* __restrict__ mpt,     // [b][256 h2][128 m][2]
    const float* __restrict__ W2,    // [512]
    const float* __restrict__ b2,    // [1]
    const float* __restrict__ bo,    // [1024]
    float* __restrict__ out,         // [2048][1024] f32
    float* __restrict__ attn_w)      // [2048][128]
{
    __shared__ __align__(16) char u[41984];      // qs|mps|w2s  then  sc
    __shared__ float rel_s[1024];                // [8][128] persistent
    __shared__ f16 Ps[8 * 136];

    const int tid = threadIdx.x;
    const int b = blockIdx.x >> 7, st = blockIdx.x & 127;
    const size_t rowbase = (size_t)b * SEQ + st * 8;
    const int w = tid >> 6, lane = tid & 63;
    const int l15 = lane & 15, l4 = lane >> 4;

    // ---------------- Phase R: relevance -> rel_s ----------------
    {
        f16* qs  = (f16*)u;                 // [8][512]  8 KB
        f16* mps = (f16*)(u + 8192);        // [64][256] 32 KB
        f16* w2s = (f16*)(u + 40960);       // [512]     1 KB

        {
            int r = tid >> 5, c = tid & 31;
            const f16* src = qcat + (rowbase + r) * QLD + 1024 + c * 16;
            *(f16x8*)(qs + r * 512 + c * 16)     = *(const f16x8*)(src);
            *(f16x8*)(qs + r * 512 + c * 16 + 8) = *(const f16x8*)(src + 8);
        }
        if (tid < 128) {
            float4 w4 = *(const float4*)(W2 + tid * 4);
            f16x4 hv = { (f16)w4.x, (f16)w4.y, (f16)w4.z, (f16)w4.w };
            *(f16x4*)(w2s + tid * 4) = hv;
        }
        const float b2v = b2[0];
        const int sg = w;

        float acc00 = 0.f, acc01 = 0.f, acc10 = 0.f, acc11 = 0.f;
        const f16* mptb = mpt + (size_t)b * 65536;

        for (int hc = 0; hc < 4; ++hc) {
            __syncthreads();
            {
                const f16x8* src = (const f16x8*)(mptb + hc * 16384);
                f16x8* dst = (f16x8*)mps;
                #pragma unroll
                for (int k = 0; k < 8; ++k) dst[tid + 256 * k] = src[tid + 256 * k];
            }
            __syncthreads();

            #pragma unroll 4
            for (int step = 0; step < 16; ++step) {
                const int habs = hc * 128 + step * 8;
                uint4 q0u = *(const uint4*)(qs + (2 * sg) * 512 + habs);
                uint4 q1u = *(const uint4*)(qs + (2 * sg + 1) * 512 + habs);
                uint4 wu  = *(const uint4*)(w2s + habs);
                const unsigned* q0p = (const unsigned*)&q0u;
                const unsigned* q1p = (const unsigned*)&q1u;
                const unsigned* wp_ = (const unsigned*)&wu;
                #pragma unroll
                for (int jj = 0; jj < 4; ++jj) {
                    uint2 mpu = *(const uint2*)(mps + ((step * 4 + jj) * 128 + 2 * lane) * 2);
                    f16x2 m0 = __builtin_bit_cast(f16x2, mpu.x);
                    f16x2 m1 = __builtin_bit_cast(f16x2, mpu.y);
                    f16x2 wp = __builtin_bit_cast(f16x2, wp_[jj]);
                    f16x2 q0 = __builtin_bit_cast(f16x2, q0p[jj]);
                    f16x2 q1 = __builtin_bit_cast(f16x2, q1p[jj]);
                    acc00 = dot2acc(relu2(q0 + m0), wp, acc00);
                    acc01 = dot2acc(relu2(q0 + m1), wp, acc01);
                    acc10 = dot2acc(relu2(q1 + m0), wp, acc10);
                    acc11 = dot2acc(relu2(q1 + m1), wp, acc11);
                }
            }
        }

        rel_s[(2 * sg) * 128 + 2 * lane]         = 1.f / (1.f + __expf(-(acc00 + b2v)));
        rel_s[(2 * sg) * 128 + 2 * lane + 1]     = 1.f / (1.f + __expf(-(acc01 + b2v)));
        rel_s[(2 * sg + 1) * 128 + 2 * lane]     = 1.f / (1.f + __expf(-(acc10 + b2v)));
        rel_s[(2 * sg + 1) * 128 + 2 * lane + 1] = 1.f / (1.f + __expf(-(acc11 + b2v)));
    }
    __syncthreads();   // rel_s ready; qs/mps dead -> sc may overwrite

    float* sc = (float*)u;   // [4][16][128] 32 KB

    // ---------------- Phase S: QK^T partials over k-quarter ----------------
    {
        f32x4 aq[8];
        #pragma unroll
        for (int n = 0; n < 8; ++n) aq[n] = (f32x4){0.f, 0.f, 0.f, 0.f};
        #pragma unroll
        for (int k4 = 0; k4 < 8; ++k4) {
            const int k0 = w * 256 + k4 * 32 + l4 * 8;
            f16x8 af = *(const f16x8*)(qcat + (rowbase + (l15 & 7)) * QLD + k0);
            #pragma unroll
            for (int n = 0; n < 8; ++n) {
                f16x8 bf = *(const f16x8*)(kvm + (size_t)(b * 128 + n * 16 + l15) * KVLD + k0);
                aq[n] = __builtin_amdgcn_mfma_f32_16x16x32_f16(af, bf, aq[n], 0, 0, 0);
            }
        }
        #pragma unroll
        for (int n = 0; n < 8; ++n)
            #pragma unroll
            for (int j = 0; j < 4; ++j)
                sc[(w * 16 + l4 * 4 + j) * 128 + n * 16 + l15] = aq[n][j];
    }
    __syncthreads();

    // ---------------- reduce partials, *rel/32, softmax ----------------
    {
        const int r = tid >> 5, seg = tid & 31;
        float4 xs = {0.f, 0.f, 0.f, 0.f};
        #pragma unroll
        for (int ww = 0; ww < 4; ++ww) {
            float4 p = *(const float4*)(sc + (ww * 16 + r) * 128 + seg * 4);
            xs.x += p.x; xs.y += p.y; xs.z += p.z; xs.w += p.w;
        }
        float4 rl = *(const float4*)(rel_s + r * 128 + seg * 4);
        float x[4];
        x[0] = xs.x * 0.03125f * rl.x; x[1] = xs.y * 0.03125f * rl.y;
        x[2] = xs.z * 0.03125f * rl.z; x[3] = xs.w * 0.03125f * rl.w;
        float mx = fmaxf(fmaxf(x[0], x[1]), fmaxf(x[2], x[3]));
        #pragma unroll
        for (int d = 1; d < 32; d <<= 1) mx = fmaxf(mx, __shfl_xor(mx, d));
        float ss = 0.f;
        #pragma unroll
        for (int c = 0; c < 4; ++c) { x[c] = __expf(x[c] - mx); ss += x[c]; }
        #pragma unroll
        for (int d = 1; d < 32; d <<= 1) ss += __shfl_xor(ss, d);
        const float inv = 1.f / ss;
        #pragma unroll
        for (int c = 0; c < 4; ++c) x[c] *= inv;
        float4 o = { x[0], x[1], x[2], x[3] };
        *(float4*)(attn_w + (rowbase + r) * 128 + seg * 4) = o;
        f16x4 ph = { (f16)x[0], (f16)x[1], (f16)x[2], (f16)x[3] };
        *(f16x4*)(Ps + r * 136 + seg * 4) = ph;
    }
    __syncthreads();

    // ---------------- Phase P: out = P @ Vo + bo over d-quarter ----------------
    {
        f16x8 pa[4];
        #pragma unroll
        for (int k = 0; k < 4; ++k)
            pa[k] = *(const f16x8*)(Ps + (l15 & 7) * 136 + k * 32 + l4 * 8);
        #pragma unroll
        for (int n2 = 0; n2 < 16; ++n2) {
            f32x4 ac = (f32x4){0.f, 0.f, 0.f, 0.f};
            const int d0 = w * 256 + n2 * 16;
            #pragma unroll
            for (int k = 0; k < 4; ++k) {
                f16x8 bf = *(const f16x8*)(VoT + (size_t)(d0 + l15) * 256 + b * 128 + k * 32 + l4 * 8);
                ac = __builtin_amdgcn_mfma_f32_16x16x32_f16(pa[k], bf, ac, 0, 0, 0);
            }
            if (l4 < 2) {
                const float bov = bo[d0 + l15];
                #pragma unroll
                for (int j = 0; j < 4; ++j)
                    out[(rowbase + l4 * 4 + j) * 1024 + d0 + l15] = ac[j] + bov;
            }
        }
    }
}

// ---------------------------------------------------------------------------
extern "C" void kernel_launch(void* const* d_in, const int* in_sizes, int n_in,
                              void* d_out, int out_size, void* d_ws, size_t ws_size,
                              hipStream_t stream)
{
    const float* hs  = (const float*)d_in[0];
    const float* mem = (const float*)d_in[1];
    const float* Wq  = (const float*)d_in[2];
    const float* bq  = (const float*)d_in[3];
    const float* Wk  = (const float*)d_in[4];
    const float* bk  = (const float*)d_in[5];
    const float* Wv  = (const float*)d_in[6];
    const float* bv  = (const float*)d_in[7];
    const float* Wo  = (const float*)d_in[8];
    const float* bo  = (const float*)d_in[9];
    const float* W1  = (const float*)d_in[10];  // (1536,512)
    const float* b1  = (const float*)d_in[11];
    const float* W2  = (const float*)d_in[12];
    const float* b2  = (const float*)d_in[13];

    float* out   = (float*)d_out;                       // (2,1024,1024)
    float* attnw = out + (size_t)BATCH * SEQ * DM;      // (2,1024,128)

    // workspace layout (16B-aligned, ~19.8 MB)
    char* wp = (char*)d_ws;
    f16* hs_f16  = (f16*)wp;  wp += (size_t)BATCH * SEQ * DM * 2;     // 4 MB
    f16* mem_f16 = (f16*)wp;  wp += (size_t)BATCH * MMEM * MEMD * 2;  // 0.25 MB
    f16* Wq_t    = (f16*)wp;  wp += (size_t)DM * DM * 2;              // 2 MB
    f16* Wo_t    = (f16*)wp;  wp += (size_t)DM * DM * 2;              // 2 MB
    f16* btcomb  = (f16*)wp;  wp += (size_t)KVLD * MEMD * 2;          // 2.5 MB
    f16* W1q_t   = (f16*)wp;  wp += (size_t)RELH * DM * 2;            // 1 MB
    f16* qcat    = (f16*)wp;  wp += (size_t)BATCH * SEQ * QLD * 2;    // 6 MB
    f16* kvm     = (f16*)wp;  wp += (size_t)BATCH * MMEM * KVLD * 2;  // 1.25 MB
    f16* VoT     = (f16*)wp;  wp += (size_t)DM * BATCH * MMEM * 2;    // 0.5 MB
    f16* mpt     = (f16*)wp;  wp += (size_t)BATCH * MMEM * RELH * 2;  // 0.25 MB

    dim3 blk(256);

    // L1: casts + weight transposes
    prep<<<dim3(2048), blk, 0, stream>>>(
        hs, mem, Wq, Wo, Wk, Wv, W1,
        hs_f16, mem_f16, Wq_t, Wo_t, btcomb, W1q_t);

    // L2: queries GEMM + kvm GEMM
    gemmA<<<dim3(336), blk, 0, stream>>>(
        hs_f16, Wq_t, bq, qcat, mem_f16, btcomb, bk, bv, b1, kvm);

    // L3: q_part GEMM + VoT GEMM + mpt
    gemmB<<<dim3(168), blk, 0, stream>>>(
        qcat, qcat, W1q_t, kvm, Wo_t, VoT, mpt);

    // L4: fused relevance + attention -> out, attn_w
    relattn<<<dim3(256), blk, 0, stream>>>(
        qcat, kvm, VoT, mpt, W2, b2, bo, out, attnw);
}